// Round 3
// baseline (3319.761 us; speedup 1.0000x reference)
//
#include <hip/hip_runtime.h>
#include <cstdint>
#include <cstddef>

// Asymm_3d_spconv: ResContextBlock + ReconBlock over submanifold sparse convs.
// Round 3: runtime dtype detection. The reference is pure fp32; the harness
// MAY have downcast float tensors to bf16 (unknowable host-side). A detect
// kernel classifies x's payload on-device (fp32 mantissa halves decode to
// huge/NaN bf16s; genuine bf16 N(0,1) data stays |v|<6), then canonicalize
// kernels produce fp32 copies of x + all weights/bn in d_ws. Main kernels
// consume canonical fp32 only; the final kernel picks output dtype from the
// same flag. All branches are data-uniform -> graph-capture safe.
//
// ws layout (float offsets): [0]=flag, [64..37824)=Wc (W1,W12,W2,W3,Wr1,Wr2,
// Wr3,bnp), [37888..)=xc, then A/B per ws_size tier (T0 all-fp32 preferred).

#define SLOPE 0.01f
#define BN_EPS 1e-5f

__device__ __forceinline__ float bflo(uint32_t w) {
    union { uint32_t i; float f; } v; v.i = w << 16; return v.f;
}
__device__ __forceinline__ float bfhi(uint32_t w) {
    union { uint32_t i; float f; } v; v.i = w & 0xffff0000u; return v.f;
}
__device__ __forceinline__ float bf2f(uint16_t u) {
    union { uint32_t i; float f; } v; v.i = ((uint32_t)u) << 16; return v.f;
}
__device__ __forceinline__ uint16_t f2bf(float f) {  // RNE
    union { float f; uint32_t i; } v; v.f = f;
    uint32_t x = v.i;
    return (uint16_t)((x + 0x7fffu + ((x >> 16) & 1u)) >> 16);
}

struct Taps9 { int t[9]; };
struct WSrcs { const void* p[8]; };

// Wc float offsets: W1 0, W12 4608, W2 13824, W3 18432, Wr1 27648,
// Wr2 30720, Wr3 33792, bnp 36864, end 37760.
#define WC_W1   0
#define WC_W12  4608
#define WC_W2   13824
#define WC_W3   18432
#define WC_WR1  27648
#define WC_WR2  30720
#define WC_WR3  33792
#define WC_BNP  36864
#define WC_END  37760

// ---------------------------------------------------------------------------
__global__ void detect_dtype(const uint16_t* __restrict__ x16, int* flag)
{
    __shared__ int s;
    if (threadIdx.x == 0) s = 0;
    __syncthreads();
    int w = 0;
    // even uint16 indices = fp32 low-mantissa halves if the payload is fp32
    for (int i = threadIdx.x * 2; i < 16384; i += 512) {
        float v = bf2f(x16[i]);
        if (!(v > -16.f && v < 16.f)) w = 1;   // NaN fails the comparison too
    }
    if (w) atomicOr(&s, 1);
    __syncthreads();
    if (threadIdx.x == 0) *flag = s;   // 1 = fp32 payload, 0 = bf16
}

__global__ void canon_weights(WSrcs srcs, float* __restrict__ Wc,
                              const int* __restrict__ flagp)
{
    const int offs[9] = {WC_W1, WC_W12, WC_W2, WC_W3, WC_WR1, WC_WR2,
                         WC_WR3, WC_BNP, WC_END};
    int i = blockIdx.x * 256 + threadIdx.x;
    if (i >= WC_END) return;
    int f32 = *flagp;
    int t = 0;
#pragma unroll
    for (int k = 1; k < 8; ++k) if (i >= offs[k]) t = k;
    int j = i - offs[t];
    Wc[i] = f32 ? ((const float*)srcs.p[t])[j]
                : bf2f(((const uint16_t*)srcs.p[t])[j]);
}

template<bool XC_F32>
__global__ void canon_x(const void* __restrict__ xsrc, void* __restrict__ xc,
                        int n4, const int* __restrict__ flagp)
{
    int f32 = *flagp;
    for (int i = blockIdx.x * blockDim.x + threadIdx.x; i < n4;
         i += gridDim.x * blockDim.x) {
        float4 v;
        if (f32) {
            v = reinterpret_cast<const float4*>(xsrc)[i];
        } else {
            ushort4 u = reinterpret_cast<const ushort4*>(xsrc)[i];
            v.x = bf2f(u.x); v.y = bf2f(u.y); v.z = bf2f(u.z); v.w = bf2f(u.w);
        }
        if constexpr (XC_F32) {
            reinterpret_cast<float4*>(xc)[i] = v;
        } else {
            ushort4 o = { f2bf(v.x), f2bf(v.y), f2bf(v.z), f2bf(v.w) };
            reinterpret_cast<ushort4*>(xc)[i] = o;
        }
    }
}

// ---------------------------------------------------------------------------
// conv(+LeakyReLU+BN)(+add). 256 thr, 128 voxels/block; thread = 4 vox x 4 ch.
// Gathered rows staged transposed fs[ci][voxel] in LDS (fp32 always).
// Weights/bn are canonical fp32.
// ---------------------------------------------------------------------------
template<int CIN, bool IN_F32, bool OUT_F32>
__launch_bounds__(256)
__global__ void conv_bn_lrelu(const void* __restrict__ feat_,
                              const int* __restrict__ nbr,
                              const float* __restrict__ Wg,   // [9,CIN,32] f32
                              const float* __restrict__ bnp,  // [4,32] f32
                              const void* __restrict__ addsrc_,
                              void* __restrict__ out_,
                              Taps9 taps, int N)
{
    __shared__ float Wl[9 * CIN * 32];
    __shared__ float fs[CIN][128];
    __shared__ int   sidx[128];
    __shared__ float bns[32], bnb[32];

    const int tid = threadIdx.x;
    const int n0  = blockIdx.x * 128;

    for (int i = tid; i < 9 * CIN * 32; i += 256)
        Wl[i] = Wg[i];
    if (tid < 32) {
        float g = bnp[tid];
        float b = bnp[32 + tid];
        float m = bnp[64 + tid];
        float v = bnp[96 + tid];
        float s = g * rsqrtf(v + BN_EPS);
        bns[tid] = s;
        bnb[tid] = b - m * s;
    }

    float acc[4][4];
#pragma unroll
    for (int v = 0; v < 4; ++v)
#pragma unroll
        for (int j = 0; j < 4; ++j) acc[v][j] = 0.f;

    const int vb = (tid >> 3) << 2;   // voxel base 0..124
    const int cg = (tid & 7) << 2;    // out-channel base 0..28
    const int r  = tid >> 1;          // staged voxel row 0..127
    const int h  = tid & 1;           // which half of input channels
    const int j0 = h * (CIN / 2);

#pragma unroll 1
    for (int t = 0; t < 9; ++t) {
        __syncthreads();  // prior fs reads done; Wl/bns ready at t==0
        if (tid < 128) {
            int n = n0 + tid;
            sidx[tid] = (n < N) ? nbr[(size_t)taps.t[t] * N + n] : -1;
        }
        __syncthreads();
        int m = sidx[r];
        if (m >= 0) {
            if constexpr (IN_F32) {
                const float* src = (const float*)feat_ + (size_t)m * CIN + j0;
#pragma unroll
                for (int q = 0; q < CIN / 2; q += 4) {
                    float4 f = *reinterpret_cast<const float4*>(src + q);
                    fs[j0 + q + 0][r] = f.x; fs[j0 + q + 1][r] = f.y;
                    fs[j0 + q + 2][r] = f.z; fs[j0 + q + 3][r] = f.w;
                }
            } else {
                const uint16_t* src = (const uint16_t*)feat_ + (size_t)m * CIN + j0;
#pragma unroll
                for (int q = 0; q < CIN / 2; q += 8) {
                    uint4 u = *reinterpret_cast<const uint4*>(src + q);
                    fs[j0 + q + 0][r] = bflo(u.x); fs[j0 + q + 1][r] = bfhi(u.x);
                    fs[j0 + q + 2][r] = bflo(u.y); fs[j0 + q + 3][r] = bfhi(u.y);
                    fs[j0 + q + 4][r] = bflo(u.z); fs[j0 + q + 5][r] = bfhi(u.z);
                    fs[j0 + q + 6][r] = bflo(u.w); fs[j0 + q + 7][r] = bfhi(u.w);
                }
            }
        } else {
#pragma unroll
            for (int q = 0; q < CIN / 2; ++q) fs[j0 + q][r] = 0.f;
        }
        __syncthreads();
        const float* wk = Wl + t * (CIN * 32) + cg;
#pragma unroll
        for (int ci = 0; ci < CIN; ++ci) {
            float4 f = *reinterpret_cast<const float4*>(&fs[ci][vb]);
            float4 w = *reinterpret_cast<const float4*>(wk + ci * 32);
            acc[0][0] += f.x * w.x; acc[0][1] += f.x * w.y; acc[0][2] += f.x * w.z; acc[0][3] += f.x * w.w;
            acc[1][0] += f.y * w.x; acc[1][1] += f.y * w.y; acc[1][2] += f.y * w.z; acc[1][3] += f.y * w.w;
            acc[2][0] += f.z * w.x; acc[2][1] += f.z * w.y; acc[2][2] += f.z * w.z; acc[2][3] += f.z * w.w;
            acc[3][0] += f.w * w.x; acc[3][1] += f.w * w.y; acc[3][2] += f.w * w.z; acc[3][3] += f.w * w.w;
        }
    }

#pragma unroll
    for (int v = 0; v < 4; ++v) {
        int n = n0 + vb + v;
        if (n >= N) continue;
        float o[4];
#pragma unroll
        for (int j = 0; j < 4; ++j) {
            float x = acc[v][j];
            x = (x >= 0.f) ? x : SLOPE * x;
            o[j] = x * bns[cg + j] + bnb[cg + j];
        }
        if (addsrc_) {
            if constexpr (OUT_F32) {
                float4 a = *reinterpret_cast<const float4*>((const float*)addsrc_ + (size_t)n * 32 + cg);
                o[0] += a.x; o[1] += a.y; o[2] += a.z; o[3] += a.w;
            } else {
                ushort4 a = *reinterpret_cast<const ushort4*>((const uint16_t*)addsrc_ + (size_t)n * 32 + cg);
                o[0] += bf2f(a.x); o[1] += bf2f(a.y); o[2] += bf2f(a.z); o[3] += bf2f(a.w);
            }
        }
        if constexpr (OUT_F32) {
            float4 st = { o[0], o[1], o[2], o[3] };
            *reinterpret_cast<float4*>((float*)out_ + (size_t)n * 32 + cg) = st;
        } else {
            ushort4 st = { f2bf(o[0]), f2bf(o[1]), f2bf(o[2]), f2bf(o[3]) };
            *reinterpret_cast<ushort4*>((uint16_t*)out_ + (size_t)n * 32 + cg) = st;
        }
    }
}

// ---------------------------------------------------------------------------
// ReconBlock: three 3-tap axial convs on y, BN scale folded into weights,
// sigmoid, sum, gate-multiply by y. Output dtype chosen by runtime flag.
// ---------------------------------------------------------------------------
__device__ __forceinline__ void acc_tile32(float (&acc)[4][4],
                                           const float (*fs)[128],
                                           const float* wk, int vb)
{
#pragma unroll
    for (int ci = 0; ci < 32; ++ci) {
        float4 f = *reinterpret_cast<const float4*>(&fs[ci][vb]);
        float4 w = *reinterpret_cast<const float4*>(wk + ci * 32);
        acc[0][0] += f.x * w.x; acc[0][1] += f.x * w.y; acc[0][2] += f.x * w.z; acc[0][3] += f.x * w.w;
        acc[1][0] += f.y * w.x; acc[1][1] += f.y * w.y; acc[1][2] += f.y * w.z; acc[1][3] += f.y * w.w;
        acc[2][0] += f.z * w.x; acc[2][1] += f.z * w.y; acc[2][2] += f.z * w.z; acc[2][3] += f.z * w.w;
        acc[3][0] += f.w * w.x; acc[3][1] += f.w * w.y; acc[3][2] += f.w * w.z; acc[3][3] += f.w * w.w;
    }
}

template<bool Y_F32>
__launch_bounds__(256)
__global__ void recon_gate(const void* __restrict__ y_,
                           const int* __restrict__ nbr,
                           const float* __restrict__ Wc,   // canonical block
                           void* __restrict__ out_,
                           const int* __restrict__ flagp, int N)
{
    __shared__ float Wl[3][3][32][32];   // BN scale folded in
    __shared__ float fs[32][128];
    __shared__ int   sidx[128];
    __shared__ float scl[3][32], shf[3][32];

    const int tid = threadIdx.x;
    const int n0  = blockIdx.x * 128;
    const int out_f32 = *flagp;

    if (tid < 96) {
        int g = tid >> 5, c = tid & 31;
        const float* p = Wc + WC_BNP + (size_t)(4 + g) * 128;  // bn_params[4+g]
        float ga = p[c];
        float be = p[32 + c];
        float mu = p[64 + c];
        float va = p[96 + c];
        float s  = ga * rsqrtf(va + BN_EPS);
        scl[g][c] = s;
        shf[g][c] = be - mu * s;
    }
    __syncthreads();
    {
        const float* Ws[3] = {Wc + WC_WR1, Wc + WC_WR2, Wc + WC_WR3};
        for (int g = 0; g < 3; ++g) {
            float* dst = &Wl[g][0][0][0];
            const float* src = Ws[g];
            for (int i = tid; i < 3 * 32 * 32; i += 256)
                dst[i] = src[i] * scl[g][i & 31];
        }
    }

    const int vb = (tid >> 3) << 2;
    const int cg = (tid & 7) << 2;
    const int r  = tid >> 1;
    const int h  = tid & 1;
    const int j0 = h * 16;

    auto gather = [&](int t) {
        __syncthreads();  // prior acc reads of fs done; Wl fold done (1st call)
        if (tid < 128) {
            int n = n0 + tid;
            sidx[tid] = (n < N) ? nbr[(size_t)t * N + n] : -1;
        }
        __syncthreads();
        int m = sidx[r];
        if (m >= 0) {
            if constexpr (Y_F32) {
                const float* src = (const float*)y_ + (size_t)m * 32 + j0;
#pragma unroll
                for (int q = 0; q < 16; q += 4) {
                    float4 f = *reinterpret_cast<const float4*>(src + q);
                    fs[j0 + q + 0][r] = f.x; fs[j0 + q + 1][r] = f.y;
                    fs[j0 + q + 2][r] = f.z; fs[j0 + q + 3][r] = f.w;
                }
            } else {
                const uint16_t* src = (const uint16_t*)y_ + (size_t)m * 32 + j0;
#pragma unroll
                for (int q = 0; q < 16; q += 8) {
                    uint4 u = *reinterpret_cast<const uint4*>(src + q);
                    fs[j0 + q + 0][r] = bflo(u.x); fs[j0 + q + 1][r] = bfhi(u.x);
                    fs[j0 + q + 2][r] = bflo(u.y); fs[j0 + q + 3][r] = bfhi(u.y);
                    fs[j0 + q + 4][r] = bflo(u.z); fs[j0 + q + 5][r] = bfhi(u.z);
                    fs[j0 + q + 6][r] = bflo(u.w); fs[j0 + q + 7][r] = bfhi(u.w);
                }
            }
        } else {
#pragma unroll
            for (int q = 0; q < 16; ++q) fs[j0 + q][r] = 0.f;
        }
        __syncthreads();
    };

    float a0[4][4], a1[4][4], a2[4][4];
#pragma unroll
    for (int v = 0; v < 4; ++v)
#pragma unroll
        for (int j = 0; j < 4; ++j) { a0[v][j] = 0.f; a1[v][j] = 0.f; a2[v][j] = 0.f; }

    // P311={4,13,22}->Wr1 k=0,1,2; P131={10,13,16}->Wr2; P113={12,13,14}->Wr3.
    // Center tap 13 last so fs still holds each voxel's own y row for gating.
    gather(4);   acc_tile32(a0, fs, &Wl[0][0][0][cg], vb);
    gather(22);  acc_tile32(a0, fs, &Wl[0][2][0][cg], vb);
    gather(10);  acc_tile32(a1, fs, &Wl[1][0][0][cg], vb);
    gather(16);  acc_tile32(a1, fs, &Wl[1][2][0][cg], vb);
    gather(12);  acc_tile32(a2, fs, &Wl[2][0][0][cg], vb);
    gather(14);  acc_tile32(a2, fs, &Wl[2][2][0][cg], vb);
    gather(13);  acc_tile32(a0, fs, &Wl[0][1][0][cg], vb);
                 acc_tile32(a1, fs, &Wl[1][1][0][cg], vb);
                 acc_tile32(a2, fs, &Wl[2][1][0][cg], vb);

#pragma unroll
    for (int v = 0; v < 4; ++v) {
        int n = n0 + vb + v;
        if (n >= N) continue;
        float o[4];
#pragma unroll
        for (int j = 0; j < 4; ++j) {
            int c = cg + j;
            float yv = fs[c][vb + v];   // center tap == voxel's own y row
            float xa = a0[v][j] + shf[0][c];
            float xb = a1[v][j] + shf[1][c];
            float xc = a2[v][j] + shf[2][c];
            float sa = 1.f / (1.f + __expf(-xa));
            float sb = 1.f / (1.f + __expf(-xb));
            float sc = 1.f / (1.f + __expf(-xc));
            o[j] = (sa + sb + sc) * yv;
        }
        if (out_f32) {
            float4 st = { o[0], o[1], o[2], o[3] };
            *reinterpret_cast<float4*>((float*)out_ + (size_t)n * 32 + cg) = st;
        } else {
            ushort4 st = { f2bf(o[0]), f2bf(o[1]), f2bf(o[2]), f2bf(o[3]) };
            *reinterpret_cast<ushort4*>((uint16_t*)out_ + (size_t)n * 32 + cg) = st;
        }
    }
}

// ---------------------------------------------------------------------------
extern "C" void kernel_launch(void* const* d_in, const int* in_sizes, int n_in,
                              void* d_out, int out_size, void* d_ws, size_t ws_size,
                              hipStream_t stream)
{
    (void)n_in; (void)out_size;
    const void* x   = d_in[0];
    const int*  nbr = (const int*)d_in[1];
    const int N  = in_sizes[0] / 16;
    const int Nx = N * 16;

    int*   flag = (int*)d_ws;
    float* Wc   = (float*)d_ws + 64;
    float* xcf  = (float*)d_ws + 37888;   // canonical x base (fp32 tiers)

    const size_t hdrB = 37888u * 4u;                    // flag + Wc
    const size_t xfB  = (size_t)Nx * 4, xhB = (size_t)Nx * 2;
    const size_t BfB  = (size_t)N * 32 * 4, BhB = (size_t)N * 32 * 2;

    dim3 block(256);
    dim3 gconv((N + 127) / 128);
    Taps9 p133 = {{9, 10, 11, 12, 13, 14, 15, 16, 17}};
    Taps9 p313 = {{3, 4, 5, 12, 13, 14, 21, 22, 23}};
    WSrcs ws8 = {{ d_in[2], d_in[3], d_in[4], d_in[5],
                   d_in[6], d_in[7], d_in[8], d_in[9] }};

    // Stage 0: detect payload dtype, canonicalize weights.
    detect_dtype<<<1, 256, 0, stream>>>((const uint16_t*)x, flag);
    canon_weights<<<(WC_END + 255) / 256, 256, 0, stream>>>(ws8, Wc, flag);

    const float* bn0 = Wc + WC_BNP + 0 * 128;
    const float* bn1 = Wc + WC_BNP + 1 * 128;
    const float* bn2 = Wc + WC_BNP + 2 * 128;
    const float* bn3 = Wc + WC_BNP + 3 * 128;

    if (ws_size >= hdrB + xfB + 2 * BfB) {
        // T0: xc fp32, A fp32(ws), B fp32(ws)
        float* A = xcf + (size_t)Nx;
        float* B = A + (size_t)N * 32;
        canon_x<true><<<1024, 256, 0, stream>>>(x, xcf, Nx / 4, flag);
        conv_bn_lrelu<16, true, true><<<gconv, block, 0, stream>>>(xcf, nbr, Wc + WC_W1,  bn0, nullptr, A, p133, N);
        conv_bn_lrelu<32, true, true><<<gconv, block, 0, stream>>>(A,   nbr, Wc + WC_W12, bn1, nullptr, B, p313, N);
        conv_bn_lrelu<16, true, true><<<gconv, block, 0, stream>>>(xcf, nbr, Wc + WC_W2,  bn2, nullptr, A, p313, N);
        conv_bn_lrelu<32, true, true><<<gconv, block, 0, stream>>>(A,   nbr, Wc + WC_W3,  bn3, B,       B, p133, N);
        recon_gate<true><<<gconv, block, 0, stream>>>(B, nbr, Wc, d_out, flag, N);
    } else if (ws_size >= hdrB + xfB + BfB) {
        // T1: xc fp32, A bf16(d_out scratch; <=9.6MB fits either dtype), B fp32(ws)
        uint16_t* A = (uint16_t*)d_out;
        float*    B = xcf + (size_t)Nx;
        canon_x<true><<<1024, 256, 0, stream>>>(x, xcf, Nx / 4, flag);
        conv_bn_lrelu<16, true,  false><<<gconv, block, 0, stream>>>(xcf, nbr, Wc + WC_W1,  bn0, nullptr, A, p133, N);
        conv_bn_lrelu<32, false, true ><<<gconv, block, 0, stream>>>(A,   nbr, Wc + WC_W12, bn1, nullptr, B, p313, N);
        conv_bn_lrelu<16, true,  false><<<gconv, block, 0, stream>>>(xcf, nbr, Wc + WC_W2,  bn2, nullptr, A, p313, N);
        conv_bn_lrelu<32, false, true ><<<gconv, block, 0, stream>>>(A,   nbr, Wc + WC_W3,  bn3, B,       B, p133, N);
        recon_gate<true><<<gconv, block, 0, stream>>>(B, nbr, Wc, d_out, flag, N);
    } else if (ws_size >= hdrB + xfB + BhB) {
        // T2: xc fp32, A bf16(d_out), B bf16(ws)
        uint16_t* A = (uint16_t*)d_out;
        uint16_t* B = (uint16_t*)(xcf + (size_t)Nx);
        canon_x<true><<<1024, 256, 0, stream>>>(x, xcf, Nx / 4, flag);
        conv_bn_lrelu<16, true,  false><<<gconv, block, 0, stream>>>(xcf, nbr, Wc + WC_W1,  bn0, nullptr, A, p133, N);
        conv_bn_lrelu<32, false, false><<<gconv, block, 0, stream>>>(A,   nbr, Wc + WC_W12, bn1, nullptr, B, p313, N);
        conv_bn_lrelu<16, true,  false><<<gconv, block, 0, stream>>>(xcf, nbr, Wc + WC_W2,  bn2, nullptr, A, p313, N);
        conv_bn_lrelu<32, false, false><<<gconv, block, 0, stream>>>(A,   nbr, Wc + WC_W3,  bn3, B,       B, p133, N);
        recon_gate<false><<<gconv, block, 0, stream>>>(B, nbr, Wc, d_out, flag, N);
    } else {
        // T3: xc bf16, A bf16(d_out), B bf16(ws)  (needs ~14.6MB)
        uint16_t* xch = (uint16_t*)xcf;
        uint16_t* A = (uint16_t*)d_out;
        uint16_t* B = (uint16_t*)(xcf + (size_t)Nx / 2);
        canon_x<false><<<1024, 256, 0, stream>>>(x, xch, Nx / 4, flag);
        conv_bn_lrelu<16, false, false><<<gconv, block, 0, stream>>>(xch, nbr, Wc + WC_W1,  bn0, nullptr, A, p133, N);
        conv_bn_lrelu<32, false, false><<<gconv, block, 0, stream>>>(A,   nbr, Wc + WC_W12, bn1, nullptr, B, p313, N);
        conv_bn_lrelu<16, false, false><<<gconv, block, 0, stream>>>(xch, nbr, Wc + WC_W2,  bn2, nullptr, A, p313, N);
        conv_bn_lrelu<32, false, false><<<gconv, block, 0, stream>>>(A,   nbr, Wc + WC_W3,  bn3, B,       B, p133, N);
        recon_gate<false><<<gconv, block, 0, stream>>>(B, nbr, Wc, d_out, flag, N);
    }
}

// Round 4
// 341.540 us; speedup vs baseline: 9.7200x; 9.7200x over previous
//
#include <hip/hip_runtime.h>
#include <cstdint>
#include <cstddef>

// Asymm_3d_spconv: ResContextBlock + ReconBlock over submanifold sparse convs.
// Round 4: recon_gate was scratch-bound (VGPR=256 cap, 6.1 GB HBM traffic from
// spilled accumulators; 92% of runtime). Restructured: the three axial conv
// groups run sequentially with ONE live acc[4][4] + running sigmoid-sum
// gsum[4][4]; gating y read directly (center tap of a submanifold conv is the
// voxel itself, nbr[13][n]==n). Per-group 12KB LDS weight buffer, 30KB total,
// __launch_bounds__(256,4) caps VGPR at 128. Convs/canon unchanged from the
// passing round-3 kernel.

#define SLOPE 0.01f
#define BN_EPS 1e-5f

__device__ __forceinline__ float bflo(uint32_t w) {
    union { uint32_t i; float f; } v; v.i = w << 16; return v.f;
}
__device__ __forceinline__ float bfhi(uint32_t w) {
    union { uint32_t i; float f; } v; v.i = w & 0xffff0000u; return v.f;
}
__device__ __forceinline__ float bf2f(uint16_t u) {
    union { uint32_t i; float f; } v; v.i = ((uint32_t)u) << 16; return v.f;
}
__device__ __forceinline__ uint16_t f2bf(float f) {  // RNE
    union { float f; uint32_t i; } v; v.f = f;
    uint32_t x = v.i;
    return (uint16_t)((x + 0x7fffu + ((x >> 16) & 1u)) >> 16);
}

struct Taps9 { int t[9]; };
struct WSrcs { const void* p[8]; };

// Wc float offsets: W1 0, W12 4608, W2 13824, W3 18432, Wr1 27648,
// Wr2 30720, Wr3 33792, bnp 36864, end 37760.
#define WC_W1   0
#define WC_W12  4608
#define WC_W2   13824
#define WC_W3   18432
#define WC_WR1  27648
#define WC_WR2  30720
#define WC_WR3  33792
#define WC_BNP  36864
#define WC_END  37760

// ---------------------------------------------------------------------------
__global__ void detect_dtype(const uint16_t* __restrict__ x16, int* flag)
{
    __shared__ int s;
    if (threadIdx.x == 0) s = 0;
    __syncthreads();
    int w = 0;
    // even uint16 indices = fp32 low-mantissa halves if the payload is fp32
    for (int i = threadIdx.x * 2; i < 16384; i += 512) {
        float v = bf2f(x16[i]);
        if (!(v > -16.f && v < 16.f)) w = 1;   // NaN fails the comparison too
    }
    if (w) atomicOr(&s, 1);
    __syncthreads();
    if (threadIdx.x == 0) *flag = s;   // 1 = fp32 payload, 0 = bf16
}

__global__ void canon_weights(WSrcs srcs, float* __restrict__ Wc,
                              const int* __restrict__ flagp)
{
    const int offs[9] = {WC_W1, WC_W12, WC_W2, WC_W3, WC_WR1, WC_WR2,
                         WC_WR3, WC_BNP, WC_END};
    int i = blockIdx.x * 256 + threadIdx.x;
    if (i >= WC_END) return;
    int f32 = *flagp;
    int t = 0;
#pragma unroll
    for (int k = 1; k < 8; ++k) if (i >= offs[k]) t = k;
    int j = i - offs[t];
    Wc[i] = f32 ? ((const float*)srcs.p[t])[j]
                : bf2f(((const uint16_t*)srcs.p[t])[j]);
}

template<bool XC_F32>
__global__ void canon_x(const void* __restrict__ xsrc, void* __restrict__ xc,
                        int n4, const int* __restrict__ flagp)
{
    int f32 = *flagp;
    for (int i = blockIdx.x * blockDim.x + threadIdx.x; i < n4;
         i += gridDim.x * blockDim.x) {
        float4 v;
        if (f32) {
            v = reinterpret_cast<const float4*>(xsrc)[i];
        } else {
            ushort4 u = reinterpret_cast<const ushort4*>(xsrc)[i];
            v.x = bf2f(u.x); v.y = bf2f(u.y); v.z = bf2f(u.z); v.w = bf2f(u.w);
        }
        if constexpr (XC_F32) {
            reinterpret_cast<float4*>(xc)[i] = v;
        } else {
            ushort4 o = { f2bf(v.x), f2bf(v.y), f2bf(v.z), f2bf(v.w) };
            reinterpret_cast<ushort4*>(xc)[i] = o;
        }
    }
}

// ---------------------------------------------------------------------------
// conv(+LeakyReLU+BN)(+add). 256 thr, 128 voxels/block; thread = 4 vox x 4 ch.
// Gathered rows staged transposed fs[ci][voxel] in LDS (fp32 always).
// ---------------------------------------------------------------------------
template<int CIN, bool IN_F32, bool OUT_F32>
__launch_bounds__(256)
__global__ void conv_bn_lrelu(const void* __restrict__ feat_,
                              const int* __restrict__ nbr,
                              const float* __restrict__ Wg,   // [9,CIN,32] f32
                              const float* __restrict__ bnp,  // [4,32] f32
                              const void* __restrict__ addsrc_,
                              void* __restrict__ out_,
                              Taps9 taps, int N)
{
    __shared__ float Wl[9 * CIN * 32];
    __shared__ float fs[CIN][128];
    __shared__ int   sidx[128];
    __shared__ float bns[32], bnb[32];

    const int tid = threadIdx.x;
    const int n0  = blockIdx.x * 128;

    for (int i = tid; i < 9 * CIN * 32; i += 256)
        Wl[i] = Wg[i];
    if (tid < 32) {
        float g = bnp[tid];
        float b = bnp[32 + tid];
        float m = bnp[64 + tid];
        float v = bnp[96 + tid];
        float s = g * rsqrtf(v + BN_EPS);
        bns[tid] = s;
        bnb[tid] = b - m * s;
    }

    float acc[4][4];
#pragma unroll
    for (int v = 0; v < 4; ++v)
#pragma unroll
        for (int j = 0; j < 4; ++j) acc[v][j] = 0.f;

    const int vb = (tid >> 3) << 2;   // voxel base 0..124
    const int cg = (tid & 7) << 2;    // out-channel base 0..28
    const int r  = tid >> 1;          // staged voxel row 0..127
    const int h  = tid & 1;           // which half of input channels
    const int j0 = h * (CIN / 2);

#pragma unroll 1
    for (int t = 0; t < 9; ++t) {
        __syncthreads();  // prior fs reads done; Wl/bns ready at t==0
        if (tid < 128) {
            int n = n0 + tid;
            sidx[tid] = (n < N) ? nbr[(size_t)taps.t[t] * N + n] : -1;
        }
        __syncthreads();
        int m = sidx[r];
        if (m >= 0) {
            if constexpr (IN_F32) {
                const float* src = (const float*)feat_ + (size_t)m * CIN + j0;
#pragma unroll
                for (int q = 0; q < CIN / 2; q += 4) {
                    float4 f = *reinterpret_cast<const float4*>(src + q);
                    fs[j0 + q + 0][r] = f.x; fs[j0 + q + 1][r] = f.y;
                    fs[j0 + q + 2][r] = f.z; fs[j0 + q + 3][r] = f.w;
                }
            } else {
                const uint16_t* src = (const uint16_t*)feat_ + (size_t)m * CIN + j0;
#pragma unroll
                for (int q = 0; q < CIN / 2; q += 8) {
                    uint4 u = *reinterpret_cast<const uint4*>(src + q);
                    fs[j0 + q + 0][r] = bflo(u.x); fs[j0 + q + 1][r] = bfhi(u.x);
                    fs[j0 + q + 2][r] = bflo(u.y); fs[j0 + q + 3][r] = bfhi(u.y);
                    fs[j0 + q + 4][r] = bflo(u.z); fs[j0 + q + 5][r] = bfhi(u.z);
                    fs[j0 + q + 6][r] = bflo(u.w); fs[j0 + q + 7][r] = bfhi(u.w);
                }
            }
        } else {
#pragma unroll
            for (int q = 0; q < CIN / 2; ++q) fs[j0 + q][r] = 0.f;
        }
        __syncthreads();
        const float* wk = Wl + t * (CIN * 32) + cg;
#pragma unroll
        for (int ci = 0; ci < CIN; ++ci) {
            float4 f = *reinterpret_cast<const float4*>(&fs[ci][vb]);
            float4 w = *reinterpret_cast<const float4*>(wk + ci * 32);
            acc[0][0] += f.x * w.x; acc[0][1] += f.x * w.y; acc[0][2] += f.x * w.z; acc[0][3] += f.x * w.w;
            acc[1][0] += f.y * w.x; acc[1][1] += f.y * w.y; acc[1][2] += f.y * w.z; acc[1][3] += f.y * w.w;
            acc[2][0] += f.z * w.x; acc[2][1] += f.z * w.y; acc[2][2] += f.z * w.z; acc[2][3] += f.z * w.w;
            acc[3][0] += f.w * w.x; acc[3][1] += f.w * w.y; acc[3][2] += f.w * w.z; acc[3][3] += f.w * w.w;
        }
    }

#pragma unroll
    for (int v = 0; v < 4; ++v) {
        int n = n0 + vb + v;
        if (n >= N) continue;
        float o[4];
#pragma unroll
        for (int j = 0; j < 4; ++j) {
            float x = acc[v][j];
            x = (x >= 0.f) ? x : SLOPE * x;
            o[j] = x * bns[cg + j] + bnb[cg + j];
        }
        if (addsrc_) {
            if constexpr (OUT_F32) {
                float4 a = *reinterpret_cast<const float4*>((const float*)addsrc_ + (size_t)n * 32 + cg);
                o[0] += a.x; o[1] += a.y; o[2] += a.z; o[3] += a.w;
            } else {
                ushort4 a = *reinterpret_cast<const ushort4*>((const uint16_t*)addsrc_ + (size_t)n * 32 + cg);
                o[0] += bf2f(a.x); o[1] += bf2f(a.y); o[2] += bf2f(a.z); o[3] += bf2f(a.w);
            }
        }
        if constexpr (OUT_F32) {
            float4 st = { o[0], o[1], o[2], o[3] };
            *reinterpret_cast<float4*>((float*)out_ + (size_t)n * 32 + cg) = st;
        } else {
            ushort4 st = { f2bf(o[0]), f2bf(o[1]), f2bf(o[2]), f2bf(o[3]) };
            *reinterpret_cast<ushort4*>((uint16_t*)out_ + (size_t)n * 32 + cg) = st;
        }
    }
}

// ---------------------------------------------------------------------------
// ReconBlock, sequential-group version. One live acc[4][4] + gsum[4][4].
// Per-group LDS weight buffer (12KB). Gating y read directly (center = self).
// ---------------------------------------------------------------------------
template<bool Y_F32>
__launch_bounds__(256, 4)
__global__ void recon_gate(const void* __restrict__ y_,
                           const int* __restrict__ nbr,
                           const float* __restrict__ Wc,   // canonical block
                           void* __restrict__ out_,
                           const int* __restrict__ flagp, int N)
{
    __shared__ float Wl[3 * 32 * 32];   // current group's BN-folded weights
    __shared__ float fs[32][128];
    __shared__ int   sidx[128];
    __shared__ float scl[3][32], shf[3][32];

    const int tid = threadIdx.x;
    const int n0  = blockIdx.x * 128;
    const int out_f32 = *flagp;

    if (tid < 96) {
        int g = tid >> 5, c = tid & 31;
        const float* p = Wc + WC_BNP + (size_t)(4 + g) * 128;  // bn_params[4+g]
        float ga = p[c];
        float be = p[32 + c];
        float mu = p[64 + c];
        float va = p[96 + c];
        float s  = ga * rsqrtf(va + BN_EPS);
        scl[g][c] = s;
        shf[g][c] = be - mu * s;
    }

    const int vb = (tid >> 3) << 2;
    const int cg = (tid & 7) << 2;
    const int r  = tid >> 1;
    const int h  = tid & 1;
    const int j0 = h * 16;

    float gsum[4][4];
#pragma unroll
    for (int v = 0; v < 4; ++v)
#pragma unroll
        for (int j = 0; j < 4; ++j) gsum[v][j] = 0.f;

    // P311={4,13,22}->Wr1; P131={10,13,16}->Wr2; P113={12,13,14}->Wr3
    const int taps[3][3] = {{4, 13, 22}, {10, 13, 16}, {12, 13, 14}};

#pragma unroll 1
    for (int g = 0; g < 3; ++g) {
        __syncthreads();   // prior group's Wl/fs reads done; scl ready (g==0)
        {
            const float* src = Wc + WC_WR1 + g * 3072;
            for (int i = tid; i < 3072; i += 256)
                Wl[i] = src[i] * scl[g][i & 31];
        }
        float acc[4][4];
#pragma unroll
        for (int v = 0; v < 4; ++v)
#pragma unroll
            for (int j = 0; j < 4; ++j) acc[v][j] = 0.f;

#pragma unroll 1
        for (int k = 0; k < 3; ++k) {
            __syncthreads();   // Wl writes (k==0) / prior fs reads done
            if (tid < 128) {
                int n = n0 + tid;
                sidx[tid] = (n < N) ? nbr[(size_t)taps[g][k] * N + n] : -1;
            }
            __syncthreads();
            int m = sidx[r];
            if (m >= 0) {
                if constexpr (Y_F32) {
                    const float* src = (const float*)y_ + (size_t)m * 32 + j0;
#pragma unroll
                    for (int q = 0; q < 16; q += 4) {
                        float4 f = *reinterpret_cast<const float4*>(src + q);
                        fs[j0 + q + 0][r] = f.x; fs[j0 + q + 1][r] = f.y;
                        fs[j0 + q + 2][r] = f.z; fs[j0 + q + 3][r] = f.w;
                    }
                } else {
                    const uint16_t* src = (const uint16_t*)y_ + (size_t)m * 32 + j0;
#pragma unroll
                    for (int q = 0; q < 16; q += 8) {
                        uint4 u = *reinterpret_cast<const uint4*>(src + q);
                        fs[j0 + q + 0][r] = bflo(u.x); fs[j0 + q + 1][r] = bfhi(u.x);
                        fs[j0 + q + 2][r] = bflo(u.y); fs[j0 + q + 3][r] = bfhi(u.y);
                        fs[j0 + q + 4][r] = bflo(u.z); fs[j0 + q + 5][r] = bfhi(u.z);
                        fs[j0 + q + 6][r] = bflo(u.w); fs[j0 + q + 7][r] = bfhi(u.w);
                    }
                }
            } else {
#pragma unroll
                for (int q = 0; q < 16; ++q) fs[j0 + q][r] = 0.f;
            }
            __syncthreads();
            const float* wk = Wl + k * (32 * 32) + cg;
#pragma unroll
            for (int ci = 0; ci < 32; ++ci) {
                float4 f = *reinterpret_cast<const float4*>(&fs[ci][vb]);
                float4 w = *reinterpret_cast<const float4*>(wk + ci * 32);
                acc[0][0] += f.x * w.x; acc[0][1] += f.x * w.y; acc[0][2] += f.x * w.z; acc[0][3] += f.x * w.w;
                acc[1][0] += f.y * w.x; acc[1][1] += f.y * w.y; acc[1][2] += f.y * w.z; acc[1][3] += f.y * w.w;
                acc[2][0] += f.z * w.x; acc[2][1] += f.z * w.y; acc[2][2] += f.z * w.z; acc[2][3] += f.z * w.w;
                acc[3][0] += f.w * w.x; acc[3][1] += f.w * w.y; acc[3][2] += f.w * w.z; acc[3][3] += f.w * w.w;
            }
        }
        // fold this group's sigmoid into the running gate sum
#pragma unroll
        for (int v = 0; v < 4; ++v)
#pragma unroll
            for (int j = 0; j < 4; ++j) {
                float x = acc[v][j] + shf[g][cg + j];
                gsum[v][j] += 1.f / (1.f + __expf(-x));
            }
    }

    // gating: y row for voxel n is y[n] (submanifold center tap = self)
#pragma unroll
    for (int v = 0; v < 4; ++v) {
        int n = n0 + vb + v;
        if (n >= N) continue;
        float yv[4];
        if constexpr (Y_F32) {
            float4 f = *reinterpret_cast<const float4*>((const float*)y_ + (size_t)n * 32 + cg);
            yv[0] = f.x; yv[1] = f.y; yv[2] = f.z; yv[3] = f.w;
        } else {
            ushort4 u = *reinterpret_cast<const ushort4*>((const uint16_t*)y_ + (size_t)n * 32 + cg);
            yv[0] = bf2f(u.x); yv[1] = bf2f(u.y); yv[2] = bf2f(u.z); yv[3] = bf2f(u.w);
        }
        if (out_f32) {
            float4 st = { gsum[v][0] * yv[0], gsum[v][1] * yv[1],
                          gsum[v][2] * yv[2], gsum[v][3] * yv[3] };
            *reinterpret_cast<float4*>((float*)out_ + (size_t)n * 32 + cg) = st;
        } else {
            ushort4 st = { f2bf(gsum[v][0] * yv[0]), f2bf(gsum[v][1] * yv[1]),
                           f2bf(gsum[v][2] * yv[2]), f2bf(gsum[v][3] * yv[3]) };
            *reinterpret_cast<ushort4*>((uint16_t*)out_ + (size_t)n * 32 + cg) = st;
        }
    }
}

// ---------------------------------------------------------------------------
extern "C" void kernel_launch(void* const* d_in, const int* in_sizes, int n_in,
                              void* d_out, int out_size, void* d_ws, size_t ws_size,
                              hipStream_t stream)
{
    (void)n_in; (void)out_size;
    const void* x   = d_in[0];
    const int*  nbr = (const int*)d_in[1];
    const int N  = in_sizes[0] / 16;
    const int Nx = N * 16;

    int*   flag = (int*)d_ws;
    float* Wc   = (float*)d_ws + 64;
    float* xcf  = (float*)d_ws + 37888;   // canonical x base (fp32 tiers)

    const size_t hdrB = 37888u * 4u;                    // flag + Wc
    const size_t xfB  = (size_t)Nx * 4;
    const size_t BfB  = (size_t)N * 32 * 4, BhB = (size_t)N * 32 * 2;

    dim3 block(256);
    dim3 gconv((N + 127) / 128);
    Taps9 p133 = {{9, 10, 11, 12, 13, 14, 15, 16, 17}};
    Taps9 p313 = {{3, 4, 5, 12, 13, 14, 21, 22, 23}};
    WSrcs ws8 = {{ d_in[2], d_in[3], d_in[4], d_in[5],
                   d_in[6], d_in[7], d_in[8], d_in[9] }};

    // Stage 0: detect payload dtype, canonicalize weights.
    detect_dtype<<<1, 256, 0, stream>>>((const uint16_t*)x, flag);
    canon_weights<<<(WC_END + 255) / 256, 256, 0, stream>>>(ws8, Wc, flag);

    const float* bn0 = Wc + WC_BNP + 0 * 128;
    const float* bn1 = Wc + WC_BNP + 1 * 128;
    const float* bn2 = Wc + WC_BNP + 2 * 128;
    const float* bn3 = Wc + WC_BNP + 3 * 128;

    if (ws_size >= hdrB + xfB + 2 * BfB) {
        // T0: xc fp32, A fp32(ws), B fp32(ws)
        float* A = xcf + (size_t)Nx;
        float* B = A + (size_t)N * 32;
        canon_x<true><<<1024, 256, 0, stream>>>(x, xcf, Nx / 4, flag);
        conv_bn_lrelu<16, true, true><<<gconv, block, 0, stream>>>(xcf, nbr, Wc + WC_W1,  bn0, nullptr, A, p133, N);
        conv_bn_lrelu<32, true, true><<<gconv, block, 0, stream>>>(A,   nbr, Wc + WC_W12, bn1, nullptr, B, p313, N);
        conv_bn_lrelu<16, true, true><<<gconv, block, 0, stream>>>(xcf, nbr, Wc + WC_W2,  bn2, nullptr, A, p313, N);
        conv_bn_lrelu<32, true, true><<<gconv, block, 0, stream>>>(A,   nbr, Wc + WC_W3,  bn3, B,       B, p133, N);
        recon_gate<true><<<gconv, block, 0, stream>>>(B, nbr, Wc, d_out, flag, N);
    } else if (ws_size >= hdrB + xfB + BfB) {
        // T1: xc fp32, A bf16(d_out scratch), B fp32(ws)
        uint16_t* A = (uint16_t*)d_out;
        float*    B = xcf + (size_t)Nx;
        canon_x<true><<<1024, 256, 0, stream>>>(x, xcf, Nx / 4, flag);
        conv_bn_lrelu<16, true,  false><<<gconv, block, 0, stream>>>(xcf, nbr, Wc + WC_W1,  bn0, nullptr, A, p133, N);
        conv_bn_lrelu<32, false, true ><<<gconv, block, 0, stream>>>(A,   nbr, Wc + WC_W12, bn1, nullptr, B, p313, N);
        conv_bn_lrelu<16, true,  false><<<gconv, block, 0, stream>>>(xcf, nbr, Wc + WC_W2,  bn2, nullptr, A, p313, N);
        conv_bn_lrelu<32, false, true ><<<gconv, block, 0, stream>>>(A,   nbr, Wc + WC_W3,  bn3, B,       B, p133, N);
        recon_gate<true><<<gconv, block, 0, stream>>>(B, nbr, Wc, d_out, flag, N);
    } else if (ws_size >= hdrB + xfB + BhB) {
        // T2: xc fp32, A bf16(d_out), B bf16(ws)
        uint16_t* A = (uint16_t*)d_out;
        uint16_t* B = (uint16_t*)(xcf + (size_t)Nx);
        canon_x<true><<<1024, 256, 0, stream>>>(x, xcf, Nx / 4, flag);
        conv_bn_lrelu<16, true,  false><<<gconv, block, 0, stream>>>(xcf, nbr, Wc + WC_W1,  bn0, nullptr, A, p133, N);
        conv_bn_lrelu<32, false, false><<<gconv, block, 0, stream>>>(A,   nbr, Wc + WC_W12, bn1, nullptr, B, p313, N);
        conv_bn_lrelu<16, true,  false><<<gconv, block, 0, stream>>>(xcf, nbr, Wc + WC_W2,  bn2, nullptr, A, p313, N);
        conv_bn_lrelu<32, false, false><<<gconv, block, 0, stream>>>(A,   nbr, Wc + WC_W3,  bn3, B,       B, p133, N);
        recon_gate<false><<<gconv, block, 0, stream>>>(B, nbr, Wc, d_out, flag, N);
    } else {
        // T3: xc bf16, A bf16(d_out), B bf16(ws)
        uint16_t* xch = (uint16_t*)xcf;
        uint16_t* A = (uint16_t*)d_out;
        uint16_t* B = (uint16_t*)(xcf + (size_t)Nx / 2);
        canon_x<false><<<1024, 256, 0, stream>>>(x, xch, Nx / 4, flag);
        conv_bn_lrelu<16, false, false><<<gconv, block, 0, stream>>>(xch, nbr, Wc + WC_W1,  bn0, nullptr, A, p133, N);
        conv_bn_lrelu<32, false, false><<<gconv, block, 0, stream>>>(A,   nbr, Wc + WC_W12, bn1, nullptr, B, p313, N);
        conv_bn_lrelu<16, false, false><<<gconv, block, 0, stream>>>(xch, nbr, Wc + WC_W2,  bn2, nullptr, A, p313, N);
        conv_bn_lrelu<32, false, false><<<gconv, block, 0, stream>>>(A,   nbr, Wc + WC_W3,  bn3, B,       B, p133, N);
        recon_gate<false><<<gconv, block, 0, stream>>>(B, nbr, Wc, d_out, flag, N);
    }
}

// Round 5
// 292.616 us; speedup vs baseline: 11.3451x; 1.1672x over previous
//
#include <hip/hip_runtime.h>
#include <cstdint>
#include <cstddef>

// Asymm_3d_spconv: ResContextBlock + ReconBlock over submanifold sparse convs.
// Round 5: MFMA rewrite. All five convs use mfma_f32_16x16x32_bf16 with a
// hi/lo bf16 split of activations AND weights (x=xh+xl; acc += Ah*Bh + Ah*Bl
// + Al*Bh; dropped Al*Bl ~ 2^-18 rel) so accuracy stays ~fp32. Intermediates
// are stored as hi/lo bf16 planes (row = 32 hi shorts | 32 lo shorts = same
// 128B as fp32), so the K-loop needs no conversions. Activations are gathered
// global->VGPR directly in A-fragment layout (m=lane&15 -> voxel row, quad ->
// K chunk, 16B/lane); all 9 taps' indices staged once -> barrier-free K-loop.
// Weights pre-split+transposed in LDS [tap][hl][co][ci pad40] (2-way bank
// aliasing = free). C-layout: col=lane&15 = out-ch, row = quad*4+reg = voxel.
// Fallback (ws too small): round-4 VALU kernels, all-bf16 tier.

#define SLOPE 0.01f
#define BN_EPS 1e-5f

typedef __attribute__((ext_vector_type(8))) short bf16x8;
typedef __attribute__((ext_vector_type(4))) float f32x4;

__device__ __forceinline__ float bflo(uint32_t w) {
    union { uint32_t i; float f; } v; v.i = w << 16; return v.f;
}
__device__ __forceinline__ float bfhi(uint32_t w) {
    union { uint32_t i; float f; } v; v.i = w & 0xffff0000u; return v.f;
}
__device__ __forceinline__ float bf2f(uint16_t u) {
    union { uint32_t i; float f; } v; v.i = ((uint32_t)u) << 16; return v.f;
}
__device__ __forceinline__ uint16_t f2bf(float f) {  // RNE
    union { float f; uint32_t i; } v; v.f = f;
    uint32_t x = v.i;
    return (uint16_t)((x + 0x7fffu + ((x >> 16) & 1u)) >> 16);
}

struct Taps9 { int t[9]; };
struct WSrcs { const void* p[8]; };

// Wc float offsets (canonical fp32 params in ws)
#define WC_W1   0
#define WC_W12  4608
#define WC_W2   13824
#define WC_W3   18432
#define WC_WR1  27648
#define WC_WR2  30720
#define WC_WR3  33792
#define WC_BNP  36864
#define WC_END  37760

// ---------------------------------------------------------------------------
__global__ void detect_dtype(const uint16_t* __restrict__ x16, int* flag)
{
    __shared__ int s;
    if (threadIdx.x == 0) s = 0;
    __syncthreads();
    int w = 0;
    for (int i = threadIdx.x * 2; i < 16384; i += 512) {
        float v = bf2f(x16[i]);
        if (!(v > -16.f && v < 16.f)) w = 1;   // NaN fails too
    }
    if (w) atomicOr(&s, 1);
    __syncthreads();
    if (threadIdx.x == 0) *flag = s;   // 1 = fp32 payload, 0 = bf16
}

__global__ void canon_weights(WSrcs srcs, float* __restrict__ Wc,
                              const int* __restrict__ flagp)
{
    const int offs[9] = {WC_W1, WC_W12, WC_W2, WC_W3, WC_WR1, WC_WR2,
                         WC_WR3, WC_BNP, WC_END};
    int i = blockIdx.x * 256 + threadIdx.x;
    if (i >= WC_END) return;
    int f32 = *flagp;
    int t = 0;
#pragma unroll
    for (int k = 1; k < 8; ++k) if (i >= offs[k]) t = k;
    int j = i - offs[t];
    Wc[i] = f32 ? ((const float*)srcs.p[t])[j]
                : bf2f(((const uint16_t*)srcs.p[t])[j]);
}

// x [N,16] (fp32 or bf16 per flag) -> hi/lo planes: row = 16 hi | 16 lo shorts
__global__ void canon_x_hl(const void* __restrict__ xsrc,
                           uint16_t* __restrict__ xhl, int N,
                           const int* __restrict__ flagp)
{
    int f32 = *flagp;
    int total = N * 16;
    for (int i = blockIdx.x * blockDim.x + threadIdx.x; i < total;
         i += gridDim.x * blockDim.x) {
        float v = f32 ? ((const float*)xsrc)[i]
                      : bf2f(((const uint16_t*)xsrc)[i]);
        int row = i >> 4, c = i & 15;
        uint16_t h = f2bf(v);
        uint16_t l = f2bf(v - bf2f(h));
        xhl[(size_t)row * 32 + c]      = h;
        xhl[(size_t)row * 32 + 16 + c] = l;
    }
}

// legacy bf16 canon for fallback tier
__global__ void canon_x_bf(const void* __restrict__ xsrc,
                           uint16_t* __restrict__ xc, int n,
                           const int* __restrict__ flagp)
{
    int f32 = *flagp;
    for (int i = blockIdx.x * blockDim.x + threadIdx.x; i < n;
         i += gridDim.x * blockDim.x) {
        float v = f32 ? ((const float*)xsrc)[i]
                      : bf2f(((const uint16_t*)xsrc)[i]);
        xc[i] = f2bf(v);
    }
}

// ---------------------------------------------------------------------------
// MFMA conv: feat rows are hi|lo bf16 (2*CIN shorts). out same format [N][64].
// 256 thr = 4 waves, 128 voxels/block; wave owns 32 voxels x 32 out-ch.
// ---------------------------------------------------------------------------
template<int CIN>
__launch_bounds__(256)
__global__ void conv_mfma(const uint16_t* __restrict__ feat,   // [N][2*CIN]
                          const int* __restrict__ nbr,
                          const float* __restrict__ Wg,        // [9][CIN][32]
                          const float* __restrict__ bnp,       // [4][32]
                          const uint16_t* __restrict__ addsrc, // nullable [N][64]
                          uint16_t* __restrict__ out,          // [N][64]
                          Taps9 taps, int N)
{
    __shared__ uint16_t Wb[9][2][32][40];   // [tap][hi/lo][co][ci pad]
    __shared__ int   sidx[9][128];
    __shared__ float bns[32], bnb[32];

    const int tid = threadIdx.x;
    const int n0  = blockIdx.x * 128;

    // stage weights: fp32 -> hi/lo bf16, transposed to [co][ci]
    for (int i = tid; i < 9 * 32 * 32; i += 256) {
        int t = i >> 10, rem = i & 1023, k = rem >> 5, co = rem & 31;
        float w = (k < CIN) ? Wg[(t * CIN + k) * 32 + co] : 0.f;
        uint16_t h = f2bf(w);
        uint16_t l = f2bf(w - bf2f(h));
        Wb[t][0][co][k] = h;
        Wb[t][1][co][k] = l;
    }
    if (tid < 32) {
        float g = bnp[tid], b = bnp[32 + tid];
        float mu = bnp[64 + tid], va = bnp[96 + tid];
        float s = g * rsqrtf(va + BN_EPS);
        bns[tid] = s;
        bnb[tid] = b - mu * s;
    }
    for (int i = tid; i < 9 * 128; i += 256) {
        int t = i >> 7, v = i & 127;
        int n = n0 + v;
        sidx[t][v] = (n < N) ? nbr[(size_t)taps.t[t] * N + n] : -1;
    }
    __syncthreads();

    const int lane = tid & 63;
    const int m = lane & 15, q = lane >> 4;
    const int vt0 = (tid >> 6) * 32;
    const bf16x8 Z8 = {0, 0, 0, 0, 0, 0, 0, 0};

    f32x4 acc[2][2];
#pragma unroll
    for (int vt = 0; vt < 2; ++vt)
#pragma unroll
        for (int ot = 0; ot < 2; ++ot) acc[vt][ot] = {0.f, 0.f, 0.f, 0.f};

#pragma unroll 1
    for (int t = 0; t < 9; ++t) {
        bf16x8 Bh0 = *(const bf16x8*)&Wb[t][0][m][q * 8];
        bf16x8 Bl0 = *(const bf16x8*)&Wb[t][1][m][q * 8];
        bf16x8 Bh1 = *(const bf16x8*)&Wb[t][0][16 + m][q * 8];
        bf16x8 Bl1 = *(const bf16x8*)&Wb[t][1][16 + m][q * 8];
#pragma unroll
        for (int vt = 0; vt < 2; ++vt) {
            int row = sidx[t][vt0 + vt * 16 + m];
            bf16x8 Ah = Z8, Al = Z8;
            if (row >= 0 && q * 8 < CIN) {
                const uint16_t* p = feat + (size_t)row * (2 * CIN) + q * 8;
                Ah = *(const bf16x8*)p;
                Al = *(const bf16x8*)(p + CIN);
            }
            acc[vt][0] = __builtin_amdgcn_mfma_f32_16x16x32_bf16(Ah, Bh0, acc[vt][0], 0, 0, 0);
            acc[vt][0] = __builtin_amdgcn_mfma_f32_16x16x32_bf16(Ah, Bl0, acc[vt][0], 0, 0, 0);
            acc[vt][0] = __builtin_amdgcn_mfma_f32_16x16x32_bf16(Al, Bh0, acc[vt][0], 0, 0, 0);
            acc[vt][1] = __builtin_amdgcn_mfma_f32_16x16x32_bf16(Ah, Bh1, acc[vt][1], 0, 0, 0);
            acc[vt][1] = __builtin_amdgcn_mfma_f32_16x16x32_bf16(Ah, Bl1, acc[vt][1], 0, 0, 0);
            acc[vt][1] = __builtin_amdgcn_mfma_f32_16x16x32_bf16(Al, Bh1, acc[vt][1], 0, 0, 0);
        }
    }

    // epilogue: C layout col=lane&15 (out-ch), row=quad*4+reg (voxel)
#pragma unroll
    for (int vt = 0; vt < 2; ++vt)
#pragma unroll
        for (int ot = 0; ot < 2; ++ot) {
            int ch = ot * 16 + m;
            float s = bns[ch], b = bnb[ch];
#pragma unroll
            for (int r = 0; r < 4; ++r) {
                int vox = n0 + vt0 + vt * 16 + q * 4 + r;
                if (vox >= N) continue;
                float x = acc[vt][ot][r];
                x = (x >= 0.f) ? x : SLOPE * x;
                float o = x * s + b;
                if (addsrc) {
                    o += bf2f(addsrc[(size_t)vox * 64 + ch]) +
                         bf2f(addsrc[(size_t)vox * 64 + 32 + ch]);
                }
                uint16_t h = f2bf(o);
                uint16_t l = f2bf(o - bf2f(h));
                out[(size_t)vox * 64 + ch]      = h;
                out[(size_t)vox * 64 + 32 + ch] = l;
            }
        }
}

// ---------------------------------------------------------------------------
// MFMA recon: 3 axial groups x 3 taps on y (hi/lo rows), BN scale folded into
// weights, per-group sigmoid summed, gate-multiply by y. Output per flag.
// ---------------------------------------------------------------------------
__launch_bounds__(256)
__global__ void recon_mfma(const uint16_t* __restrict__ y,   // [N][64]
                           const int* __restrict__ nbr,
                           const float* __restrict__ Wc,
                           void* __restrict__ out_,
                           const int* __restrict__ flagp, int N)
{
    __shared__ uint16_t Wb[9][2][32][40];
    __shared__ int   sidx[9][128];
    __shared__ float scl[3][32], shf[3][32];

    const int tid = threadIdx.x;
    const int n0  = blockIdx.x * 128;
    const int out_f32 = *flagp;

    if (tid < 96) {
        int g = tid >> 5, c = tid & 31;
        const float* p = Wc + WC_BNP + (size_t)(4 + g) * 128;
        float ga = p[c], be = p[32 + c], mu = p[64 + c], va = p[96 + c];
        float s = ga * rsqrtf(va + BN_EPS);
        scl[g][c] = s;
        shf[g][c] = be - mu * s;
    }
    __syncthreads();

    // taps: group g uses 13 + stride*(k-1), stride = 9,3,1 -> {4,13,22},{10,13,16},{12,13,14}
    for (int i = tid; i < 9 * 32 * 32; i += 256) {
        int t = i >> 10, rem = i & 1023, k = rem >> 5, co = rem & 31;
        int g = t / 3, kk = t - g * 3;
        float w = Wc[WC_WR1 + g * 3072 + kk * 1024 + k * 32 + co] * scl[g][co];
        uint16_t h = f2bf(w);
        uint16_t l = f2bf(w - bf2f(h));
        Wb[t][0][co][k] = h;
        Wb[t][1][co][k] = l;
    }
    for (int i = tid; i < 9 * 128; i += 256) {
        int t = i >> 7, v = i & 127;
        int g = t / 3, kk = t - g * 3;
        int stride = (g == 0) ? 9 : (g == 1) ? 3 : 1;
        int tap = 13 + stride * (kk - 1);
        int n = n0 + v;
        sidx[t][v] = (n < N) ? nbr[(size_t)tap * N + n] : -1;
    }
    __syncthreads();

    const int lane = tid & 63;
    const int m = lane & 15, q = lane >> 4;
    const int vt0 = (tid >> 6) * 32;
    const bf16x8 Z8 = {0, 0, 0, 0, 0, 0, 0, 0};

    f32x4 gsum[2][2];
#pragma unroll
    for (int vt = 0; vt < 2; ++vt)
#pragma unroll
        for (int ot = 0; ot < 2; ++ot) gsum[vt][ot] = {0.f, 0.f, 0.f, 0.f};

#pragma unroll 1
    for (int g = 0; g < 3; ++g) {
        f32x4 acc[2][2];
#pragma unroll
        for (int vt = 0; vt < 2; ++vt)
#pragma unroll
            for (int ot = 0; ot < 2; ++ot) acc[vt][ot] = {0.f, 0.f, 0.f, 0.f};

#pragma unroll 1
        for (int kk = 0; kk < 3; ++kk) {
            int t = g * 3 + kk;
            bf16x8 Bh0 = *(const bf16x8*)&Wb[t][0][m][q * 8];
            bf16x8 Bl0 = *(const bf16x8*)&Wb[t][1][m][q * 8];
            bf16x8 Bh1 = *(const bf16x8*)&Wb[t][0][16 + m][q * 8];
            bf16x8 Bl1 = *(const bf16x8*)&Wb[t][1][16 + m][q * 8];
#pragma unroll
            for (int vt = 0; vt < 2; ++vt) {
                int row = sidx[t][vt0 + vt * 16 + m];
                bf16x8 Ah = Z8, Al = Z8;
                if (row >= 0) {
                    const uint16_t* p = y + (size_t)row * 64 + q * 8;
                    Ah = *(const bf16x8*)p;
                    Al = *(const bf16x8*)(p + 32);
                }
                acc[vt][0] = __builtin_amdgcn_mfma_f32_16x16x32_bf16(Ah, Bh0, acc[vt][0], 0, 0, 0);
                acc[vt][0] = __builtin_amdgcn_mfma_f32_16x16x32_bf16(Ah, Bl0, acc[vt][0], 0, 0, 0);
                acc[vt][0] = __builtin_amdgcn_mfma_f32_16x16x32_bf16(Al, Bh0, acc[vt][0], 0, 0, 0);
                acc[vt][1] = __builtin_amdgcn_mfma_f32_16x16x32_bf16(Ah, Bh1, acc[vt][1], 0, 0, 0);
                acc[vt][1] = __builtin_amdgcn_mfma_f32_16x16x32_bf16(Ah, Bl1, acc[vt][1], 0, 0, 0);
                acc[vt][1] = __builtin_amdgcn_mfma_f32_16x16x32_bf16(Al, Bh1, acc[vt][1], 0, 0, 0);
            }
        }
#pragma unroll
        for (int vt = 0; vt < 2; ++vt)
#pragma unroll
            for (int ot = 0; ot < 2; ++ot) {
                float sh = shf[g][ot * 16 + m];
#pragma unroll
                for (int r = 0; r < 4; ++r) {
                    float x = acc[vt][ot][r] + sh;
                    gsum[vt][ot][r] += 1.f / (1.f + __expf(-x));
                }
            }
    }

#pragma unroll
    for (int vt = 0; vt < 2; ++vt)
#pragma unroll
        for (int ot = 0; ot < 2; ++ot) {
            int ch = ot * 16 + m;
#pragma unroll
            for (int r = 0; r < 4; ++r) {
                int vox = n0 + vt0 + vt * 16 + q * 4 + r;
                if (vox >= N) continue;
                float yv = bf2f(y[(size_t)vox * 64 + ch]) +
                           bf2f(y[(size_t)vox * 64 + 32 + ch]);
                float o = gsum[vt][ot][r] * yv;
                if (out_f32)
                    ((float*)out_)[(size_t)vox * 32 + ch] = o;
                else
                    ((uint16_t*)out_)[(size_t)vox * 32 + ch] = f2bf(o);
            }
        }
}

// ---------------------------------------------------------------------------
// Fallback VALU kernels (round-4, proven) for the all-bf16 small-ws tier.
// ---------------------------------------------------------------------------
template<int CIN>
__launch_bounds__(256)
__global__ void conv_bn_lrelu_bf(const uint16_t* __restrict__ feat,
                                 const int* __restrict__ nbr,
                                 const float* __restrict__ Wg,
                                 const float* __restrict__ bnp,
                                 const uint16_t* __restrict__ addsrc,
                                 uint16_t* __restrict__ out,
                                 Taps9 taps, int N)
{
    __shared__ float Wl[9 * CIN * 32];
    __shared__ float fs[CIN][128];
    __shared__ int   sidx[128];
    __shared__ float bns[32], bnb[32];

    const int tid = threadIdx.x;
    const int n0  = blockIdx.x * 128;

    for (int i = tid; i < 9 * CIN * 32; i += 256) Wl[i] = Wg[i];
    if (tid < 32) {
        float g = bnp[tid], b = bnp[32 + tid];
        float mu = bnp[64 + tid], va = bnp[96 + tid];
        float s = g * rsqrtf(va + BN_EPS);
        bns[tid] = s; bnb[tid] = b - mu * s;
    }
    float acc[4][4];
#pragma unroll
    for (int v = 0; v < 4; ++v)
#pragma unroll
        for (int j = 0; j < 4; ++j) acc[v][j] = 0.f;

    const int vb = (tid >> 3) << 2, cg = (tid & 7) << 2;
    const int r = tid >> 1, h = tid & 1, j0 = h * (CIN / 2);

#pragma unroll 1
    for (int t = 0; t < 9; ++t) {
        __syncthreads();
        if (tid < 128) {
            int n = n0 + tid;
            sidx[tid] = (n < N) ? nbr[(size_t)taps.t[t] * N + n] : -1;
        }
        __syncthreads();
        int mm = sidx[r];
        if (mm >= 0) {
            const uint16_t* src = feat + (size_t)mm * CIN + j0;
#pragma unroll
            for (int qq = 0; qq < CIN / 2; qq += 8) {
                uint4 u = *reinterpret_cast<const uint4*>(src + qq);
                fs[j0 + qq + 0][r] = bflo(u.x); fs[j0 + qq + 1][r] = bfhi(u.x);
                fs[j0 + qq + 2][r] = bflo(u.y); fs[j0 + qq + 3][r] = bfhi(u.y);
                fs[j0 + qq + 4][r] = bflo(u.z); fs[j0 + qq + 5][r] = bfhi(u.z);
                fs[j0 + qq + 6][r] = bflo(u.w); fs[j0 + qq + 7][r] = bfhi(u.w);
            }
        } else {
#pragma unroll
            for (int qq = 0; qq < CIN / 2; ++qq) fs[j0 + qq][r] = 0.f;
        }
        __syncthreads();
        const float* wk = Wl + t * (CIN * 32) + cg;
#pragma unroll
        for (int ci = 0; ci < CIN; ++ci) {
            float4 f = *reinterpret_cast<const float4*>(&fs[ci][vb]);
            float4 w = *reinterpret_cast<const float4*>(wk + ci * 32);
            acc[0][0] += f.x * w.x; acc[0][1] += f.x * w.y; acc[0][2] += f.x * w.z; acc[0][3] += f.x * w.w;
            acc[1][0] += f.y * w.x; acc[1][1] += f.y * w.y; acc[1][2] += f.y * w.z; acc[1][3] += f.y * w.w;
            acc[2][0] += f.z * w.x; acc[2][1] += f.z * w.y; acc[2][2] += f.z * w.z; acc[2][3] += f.z * w.w;
            acc[3][0] += f.w * w.x; acc[3][1] += f.w * w.y; acc[3][2] += f.w * w.z; acc[3][3] += f.w * w.w;
        }
    }
#pragma unroll
    for (int v = 0; v < 4; ++v) {
        int n = n0 + vb + v;
        if (n >= N) continue;
        ushort4 st;
        uint16_t* ov = (uint16_t*)&st;
#pragma unroll
        for (int j = 0; j < 4; ++j) {
            float x = acc[v][j];
            x = (x >= 0.f) ? x : SLOPE * x;
            float o = x * bns[cg + j] + bnb[cg + j];
            if (addsrc) o += bf2f(addsrc[(size_t)n * 32 + cg + j]);
            ov[j] = f2bf(o);
        }
        *reinterpret_cast<ushort4*>(out + (size_t)n * 32 + cg) = st;
    }
}

__launch_bounds__(256, 4)
__global__ void recon_gate_bf(const uint16_t* __restrict__ y,
                              const int* __restrict__ nbr,
                              const float* __restrict__ Wc,
                              void* __restrict__ out_,
                              const int* __restrict__ flagp, int N)
{
    __shared__ float Wl[3 * 32 * 32];
    __shared__ float fs[32][128];
    __shared__ int   sidx[128];
    __shared__ float scl[3][32], shf[3][32];

    const int tid = threadIdx.x;
    const int n0  = blockIdx.x * 128;
    const int out_f32 = *flagp;

    if (tid < 96) {
        int g = tid >> 5, c = tid & 31;
        const float* p = Wc + WC_BNP + (size_t)(4 + g) * 128;
        float ga = p[c], be = p[32 + c], mu = p[64 + c], va = p[96 + c];
        float s = ga * rsqrtf(va + BN_EPS);
        scl[g][c] = s; shf[g][c] = be - mu * s;
    }
    const int vb = (tid >> 3) << 2, cg = (tid & 7) << 2;
    const int r = tid >> 1, h = tid & 1, j0 = h * 16;

    float gsum[4][4];
#pragma unroll
    for (int v = 0; v < 4; ++v)
#pragma unroll
        for (int j = 0; j < 4; ++j) gsum[v][j] = 0.f;

    const int taps[3][3] = {{4, 13, 22}, {10, 13, 16}, {12, 13, 14}};

#pragma unroll 1
    for (int g = 0; g < 3; ++g) {
        __syncthreads();
        {
            const float* src = Wc + WC_WR1 + g * 3072;
            for (int i = tid; i < 3072; i += 256)
                Wl[i] = src[i] * scl[g][i & 31];
        }
        float acc[4][4];
#pragma unroll
        for (int v = 0; v < 4; ++v)
#pragma unroll
            for (int j = 0; j < 4; ++j) acc[v][j] = 0.f;

#pragma unroll 1
        for (int k = 0; k < 3; ++k) {
            __syncthreads();
            if (tid < 128) {
                int n = n0 + tid;
                sidx[tid] = (n < N) ? nbr[(size_t)taps[g][k] * N + n] : -1;
            }
            __syncthreads();
            int mm = sidx[r];
            if (mm >= 0) {
                const uint16_t* src = y + (size_t)mm * 32 + j0;
#pragma unroll
                for (int qq = 0; qq < 16; qq += 8) {
                    uint4 u = *reinterpret_cast<const uint4*>(src + qq);
                    fs[j0 + qq + 0][r] = bflo(u.x); fs[j0 + qq + 1][r] = bfhi(u.x);
                    fs[j0 + qq + 2][r] = bflo(u.y); fs[j0 + qq + 3][r] = bfhi(u.y);
                    fs[j0 + qq + 4][r] = bflo(u.z); fs[j0 + qq + 5][r] = bfhi(u.z);
                    fs[j0 + qq + 6][r] = bflo(u.w); fs[j0 + qq + 7][r] = bfhi(u.w);
                }
            } else {
#pragma unroll
                for (int qq = 0; qq < 16; ++qq) fs[j0 + qq][r] = 0.f;
            }
            __syncthreads();
            const float* wk = Wl + k * (32 * 32) + cg;
#pragma unroll
            for (int ci = 0; ci < 32; ++ci) {
                float4 f = *reinterpret_cast<const float4*>(&fs[ci][vb]);
                float4 w = *reinterpret_cast<const float4*>(wk + ci * 32);
                acc[0][0] += f.x * w.x; acc[0][1] += f.x * w.y; acc[0][2] += f.x * w.z; acc[0][3] += f.x * w.w;
                acc[1][0] += f.y * w.x; acc[1][1] += f.y * w.y; acc[1][2] += f.y * w.z; acc[1][3] += f.y * w.w;
                acc[2][0] += f.z * w.x; acc[2][1] += f.z * w.y; acc[2][2] += f.z * w.z; acc[2][3] += f.z * w.w;
                acc[3][0] += f.w * w.x; acc[3][1] += f.w * w.y; acc[3][2] += f.w * w.z; acc[3][3] += f.w * w.w;
            }
        }
#pragma unroll
        for (int v = 0; v < 4; ++v)
#pragma unroll
            for (int j = 0; j < 4; ++j) {
                float x = acc[v][j] + shf[g][cg + j];
                gsum[v][j] += 1.f / (1.f + __expf(-x));
            }
    }
#pragma unroll
    for (int v = 0; v < 4; ++v) {
        int n = n0 + vb + v;
        if (n >= N) continue;
#pragma unroll
        for (int j = 0; j < 4; ++j) {
            float yv = bf2f(y[(size_t)n * 32 + cg + j]);
            float o = gsum[v][j] * yv;
            if (out_f32) ((float*)out_)[(size_t)n * 32 + cg + j] = o;
            else ((uint16_t*)out_)[(size_t)n * 32 + cg + j] = f2bf(o);
        }
    }
}

// ---------------------------------------------------------------------------
extern "C" void kernel_launch(void* const* d_in, const int* in_sizes, int n_in,
                              void* d_out, int out_size, void* d_ws, size_t ws_size,
                              hipStream_t stream)
{
    (void)n_in; (void)out_size;
    const void* x   = d_in[0];
    const int*  nbr = (const int*)d_in[1];
    const int N  = in_sizes[0] / 16;

    int*   flag = (int*)d_ws;
    float* Wc   = (float*)d_ws + 64;

    const size_t hdrB = 37888u * 4u;
    const size_t xhlB = (size_t)N * 32 * 2;   // 9.6 MB
    const size_t plnB = (size_t)N * 64 * 2;   // 19.2 MB

    dim3 block(256);
    dim3 gconv((N + 127) / 128);
    Taps9 p133 = {{9, 10, 11, 12, 13, 14, 15, 16, 17}};
    Taps9 p313 = {{3, 4, 5, 12, 13, 14, 21, 22, 23}};
    WSrcs ws8 = {{ d_in[2], d_in[3], d_in[4], d_in[5],
                   d_in[6], d_in[7], d_in[8], d_in[9] }};

    detect_dtype<<<1, 256, 0, stream>>>((const uint16_t*)x, flag);
    canon_weights<<<(WC_END + 255) / 256, 256, 0, stream>>>(ws8, Wc, flag);

    const float* bn0 = Wc + WC_BNP + 0 * 128;
    const float* bn1 = Wc + WC_BNP + 1 * 128;
    const float* bn2 = Wc + WC_BNP + 2 * 128;
    const float* bn3 = Wc + WC_BNP + 3 * 128;

    if (ws_size >= hdrB + xhlB + 2 * plnB) {
        // MFMA path: hi/lo bf16 planes everywhere, ~fp32 accuracy
        uint16_t* xhl = (uint16_t*)((char*)d_ws + hdrB);
        uint16_t* A   = xhl + (size_t)N * 32;
        uint16_t* B   = A + (size_t)N * 64;
        canon_x_hl<<<1024, 256, 0, stream>>>(x, xhl, N, flag);
        conv_mfma<16><<<gconv, block, 0, stream>>>(xhl, nbr, Wc + WC_W1,  bn0, nullptr, A, p133, N);
        conv_mfma<32><<<gconv, block, 0, stream>>>(A,   nbr, Wc + WC_W12, bn1, nullptr, B, p313, N);
        conv_mfma<16><<<gconv, block, 0, stream>>>(xhl, nbr, Wc + WC_W2,  bn2, nullptr, A, p313, N);
        conv_mfma<32><<<gconv, block, 0, stream>>>(A,   nbr, Wc + WC_W3,  bn3, B,       B, p133, N);
        recon_mfma<<<gconv, block, 0, stream>>>(B, nbr, Wc, d_out, flag, N);
    } else {
        // fallback: all-bf16 VALU tier (A in d_out scratch, B in ws)
        uint16_t* xc = (uint16_t*)((char*)d_ws + hdrB);
        uint16_t* A  = (uint16_t*)d_out;
        uint16_t* B  = xc + (size_t)N * 16;
        canon_x_bf<<<1024, 256, 0, stream>>>(x, xc, N * 16, flag);
        conv_bn_lrelu_bf<16><<<gconv, block, 0, stream>>>(xc, nbr, Wc + WC_W1,  bn0, nullptr, A, p133, N);
        conv_bn_lrelu_bf<32><<<gconv, block, 0, stream>>>(A,  nbr, Wc + WC_W12, bn1, nullptr, B, p313, N);
        conv_bn_lrelu_bf<16><<<gconv, block, 0, stream>>>(xc, nbr, Wc + WC_W2,  bn2, nullptr, A, p313, N);
        conv_bn_lrelu_bf<32><<<gconv, block, 0, stream>>>(A,  nbr, Wc + WC_W3,  bn3, B,       B, p133, N);
        recon_gate_bf<<<gconv, block, 0, stream>>>(B, nbr, Wc, d_out, flag, N);
    }
}

// Round 6
// 239.068 us; speedup vs baseline: 13.8863x; 1.2240x over previous
//
#include <hip/hip_runtime.h>
#include <cstdint>
#include <cstddef>

// Asymm_3d_spconv: ResContextBlock + ReconBlock over submanifold sparse convs.
// Round 6: convs were latency/overhead-bound (MfmaUtil 6%, 2.7M LDS bank
// conflicts, per-block weight re-staging). Changes:
//  - prep_weights: one-time global hi/lo B-fragment weight layout for all 5
//    stages; conv kernels load B-frags from global (L1/L2-hot), LDS = sidx only.
//  - fully unrolled 9-tap K-loop (launch_bounds(256,3), <=170 VGPR) so gathers
//    pipeline.
//  - CIN=16 stages: A row [16h|16l] is exactly K=32 -> acc += A*[wh|wh] +
//    A*[wl|0] = same 3-term hi/lo product with 1 A-load + 4 MFMAs.
//  - fused dispatches (ws permitting): D1=conv1||conv2, D2=conv12||conv3,
//    D3=add_y (y=s+r), D4=recon. Sequential + VALU fallback tiers retained.

#define SLOPE 0.01f
#define BN_EPS 1e-5f

typedef __attribute__((ext_vector_type(8))) short bf16x8;
typedef __attribute__((ext_vector_type(4))) float f32x4;

__device__ __forceinline__ float bflo(uint32_t w) {
    union { uint32_t i; float f; } v; v.i = w << 16; return v.f;
}
__device__ __forceinline__ float bfhi(uint32_t w) {
    union { uint32_t i; float f; } v; v.i = w & 0xffff0000u; return v.f;
}
__device__ __forceinline__ float bf2f(uint16_t u) {
    union { uint32_t i; float f; } v; v.i = ((uint32_t)u) << 16; return v.f;
}
__device__ __forceinline__ uint16_t f2bf(float f) {  // RNE
    union { float f; uint32_t i; } v; v.f = f;
    uint32_t x = v.i;
    return (uint16_t)((x + 0x7fffu + ((x >> 16) & 1u)) >> 16);
}

struct Taps9 { int t[9]; };
struct WSrcs { const void* p[8]; };

// Wc float offsets (canonical fp32 params in ws)
#define WC_W1   0
#define WC_W12  4608
#define WC_W2   13824
#define WC_W3   18432
#define WC_WR1  27648
#define WC_WR2  30720
#define WC_WR3  33792
#define WC_BNP  36864
#define WC_END  37760

// prepped weights: [stage5][tap9][hl2][co32][k32] shorts
#define WF_STAGE 18432
#define WF_TOTAL 92160

// ---------------------------------------------------------------------------
__global__ void detect_dtype(const uint16_t* __restrict__ x16, int* flag)
{
    __shared__ int s;
    if (threadIdx.x == 0) s = 0;
    __syncthreads();
    int w = 0;
    for (int i = threadIdx.x * 2; i < 16384; i += 512) {
        float v = bf2f(x16[i]);
        if (!(v > -16.f && v < 16.f)) w = 1;   // NaN fails too
    }
    if (w) atomicOr(&s, 1);
    __syncthreads();
    if (threadIdx.x == 0) *flag = s;   // 1 = fp32 payload, 0 = bf16
}

__global__ void canon_weights(WSrcs srcs, float* __restrict__ Wc,
                              const int* __restrict__ flagp)
{
    const int offs[9] = {WC_W1, WC_W12, WC_W2, WC_W3, WC_WR1, WC_WR2,
                         WC_WR3, WC_BNP, WC_END};
    int i = blockIdx.x * 256 + threadIdx.x;
    if (i >= WC_END) return;
    int f32 = *flagp;
    int t = 0;
#pragma unroll
    for (int k = 1; k < 8; ++k) if (i >= offs[k]) t = k;
    int j = i - offs[t];
    Wc[i] = f32 ? ((const float*)srcs.p[t])[j]
                : bf2f(((const uint16_t*)srcs.p[t])[j]);
}

// Build B-fragment-ready hi/lo weights. Stages 0,2 (CIN16): hl=0 -> [wh|wh]
// duplicated halves, hl=1 -> [wl|0]. Stages 1,3,4 (CIN32): hl=0 -> wh,
// hl=1 -> wl. Stage 4 folds the recon BN scale into the weights.
__global__ void prep_weights(const float* __restrict__ Wc,
                             uint16_t* __restrict__ Wf)
{
    int i = blockIdx.x * 256 + threadIdx.x;
    if (i >= WF_TOTAL) return;
    int s  = i / WF_STAGE, r = i - s * WF_STAGE;
    int t  = r >> 11, r2 = r & 2047;
    int hl = r2 >> 10, r3 = r2 & 1023;
    int co = r3 >> 5,  k = r3 & 31;

    uint16_t outv;
    if (s == 0 || s == 2) {
        int off = (s == 0) ? WC_W1 : WC_W2;
        int kk = k & 15;
        float w = Wc[off + (t * 16 + kk) * 32 + co];
        uint16_t h = f2bf(w);
        if (hl == 0) outv = h;                                  // [wh|wh]
        else         outv = (k < 16) ? f2bf(w - bf2f(h)) : 0;   // [wl|0]
    } else {
        float w;
        if (s == 4) {
            int g = t / 3, kk = t - g * 3;
            const float* p = Wc + WC_BNP + (size_t)(4 + g) * 128;
            float scl = p[co] * rsqrtf(p[96 + co] + BN_EPS);
            w = Wc[WC_WR1 + g * 3072 + kk * 1024 + k * 32 + co] * scl;
        } else {
            int off = (s == 1) ? WC_W12 : WC_W3;
            w = Wc[off + (t * 32 + k) * 32 + co];
        }
        uint16_t h = f2bf(w);
        outv = (hl == 0) ? h : f2bf(w - bf2f(h));
    }
    Wf[i] = outv;
}

// x [N,16] -> hi/lo rows: 16 hi | 16 lo shorts
__global__ void canon_x_hl(const void* __restrict__ xsrc,
                           uint16_t* __restrict__ xhl, int N,
                           const int* __restrict__ flagp)
{
    int f32 = *flagp;
    int total = N * 16;
    for (int i = blockIdx.x * blockDim.x + threadIdx.x; i < total;
         i += gridDim.x * blockDim.x) {
        float v = f32 ? ((const float*)xsrc)[i]
                      : bf2f(((const uint16_t*)xsrc)[i]);
        int row = i >> 4, c = i & 15;
        uint16_t h = f2bf(v);
        uint16_t l = f2bf(v - bf2f(h));
        xhl[(size_t)row * 32 + c]      = h;
        xhl[(size_t)row * 32 + 16 + c] = l;
    }
}

__global__ void canon_x_bf(const void* __restrict__ xsrc,
                           uint16_t* __restrict__ xc, int n,
                           const int* __restrict__ flagp)
{
    int f32 = *flagp;
    for (int i = blockIdx.x * blockDim.x + threadIdx.x; i < n;
         i += gridDim.x * blockDim.x) {
        float v = f32 ? ((const float*)xsrc)[i]
                      : bf2f(((const uint16_t*)xsrc)[i]);
        xc[i] = f2bf(v);
    }
}

// y = s + r (hi/lo rows [N][64] shorts), chunk of 8 channels per thread
__global__ void add_y(const uint16_t* __restrict__ s,
                      const uint16_t* __restrict__ r,
                      uint16_t* __restrict__ y, int n4)
{
    for (int i = blockIdx.x * blockDim.x + threadIdx.x; i < n4;
         i += gridDim.x * blockDim.x) {
        int row = i >> 2, c = i & 3;
        size_t bh = (size_t)row * 64 + c * 8;
        size_t bl = bh + 32;
        uint4 shv = *(const uint4*)(s + bh), slv = *(const uint4*)(s + bl);
        uint4 rhv = *(const uint4*)(r + bh), rlv = *(const uint4*)(r + bl);
        const uint32_t* sh = &shv.x; const uint32_t* sl = &slv.x;
        const uint32_t* rh = &rhv.x; const uint32_t* rl = &rlv.x;
        uint16_t oh[8], ol[8];
#pragma unroll
        for (int j = 0; j < 4; ++j) {
            float v0 = bflo(sh[j]) + bflo(sl[j]) + bflo(rh[j]) + bflo(rl[j]);
            float v1 = bfhi(sh[j]) + bfhi(sl[j]) + bfhi(rh[j]) + bfhi(rl[j]);
            oh[2*j]   = f2bf(v0); ol[2*j]   = f2bf(v0 - bf2f(oh[2*j]));
            oh[2*j+1] = f2bf(v1); ol[2*j+1] = f2bf(v1 - bf2f(oh[2*j+1]));
        }
        *(uint4*)(y + bh) = *(const uint4*)oh;
        *(uint4*)(y + bl) = *(const uint4*)ol;
    }
}

// ---------------------------------------------------------------------------
// MFMA conv v2. 256 thr = 4 waves, 128 voxels/block; wave: 32 vox x 32 co.
// B-frags from prepped global weights; LDS holds only sidx.
// ---------------------------------------------------------------------------
struct ConvJob {
    const uint16_t* feat;    // [N][2*CIN] hi/lo rows
    const uint16_t* Wf;      // stage base, [9][2][32][32]
    const float*    bn;      // [4][32] fp32
    const uint16_t* addsrc;  // nullable [N][64]
    uint16_t*       out;     // [N][64]
    Taps9 taps;
};

template<int CIN>
__launch_bounds__(256, 3)
__global__ void conv_mfma2(ConvJob j0, ConvJob j1,
                           const int* __restrict__ nbr, int N)
{
    __shared__ int sidx[9][128];
    const ConvJob J = (blockIdx.y == 1) ? j1 : j0;
    const int tid = threadIdx.x;
    const int n0  = blockIdx.x * 128;

    for (int i = tid; i < 9 * 128; i += 256) {
        int t = i >> 7, v = i & 127, n = n0 + v;
        sidx[t][v] = (n < N) ? nbr[(size_t)J.taps.t[t] * N + n] : -1;
    }
    __syncthreads();

    const int lane = tid & 63;
    const int m = lane & 15, q = lane >> 4;
    const int vt0 = (tid >> 6) * 32;
    const bf16x8 Z8 = {0, 0, 0, 0, 0, 0, 0, 0};

    f32x4 acc[2][2];
#pragma unroll
    for (int vt = 0; vt < 2; ++vt)
#pragma unroll
        for (int ot = 0; ot < 2; ++ot) acc[vt][ot] = {0.f, 0.f, 0.f, 0.f};

#pragma unroll
    for (int t = 0; t < 9; ++t) {
        const uint16_t* wb = J.Wf + t * 2048;
        bf16x8 B00 = *(const bf16x8*)(wb +        m * 32 + q * 8);        // hl0 ot0
        bf16x8 B10 = *(const bf16x8*)(wb + 1024 + m * 32 + q * 8);        // hl1 ot0
        bf16x8 B01 = *(const bf16x8*)(wb +        (16 + m) * 32 + q * 8); // hl0 ot1
        bf16x8 B11 = *(const bf16x8*)(wb + 1024 + (16 + m) * 32 + q * 8); // hl1 ot1
#pragma unroll
        for (int vt = 0; vt < 2; ++vt) {
            int row = sidx[t][vt0 + vt * 16 + m];
            if constexpr (CIN == 16) {
                // A row [16h|16l] = K32; acc += A*[wh|wh] + A*[wl|0]
                bf16x8 A = Z8;
                if (row >= 0)
                    A = *(const bf16x8*)(J.feat + (size_t)row * 32 + q * 8);
                acc[vt][0] = __builtin_amdgcn_mfma_f32_16x16x32_bf16(A, B00, acc[vt][0], 0, 0, 0);
                acc[vt][0] = __builtin_amdgcn_mfma_f32_16x16x32_bf16(A, B10, acc[vt][0], 0, 0, 0);
                acc[vt][1] = __builtin_amdgcn_mfma_f32_16x16x32_bf16(A, B01, acc[vt][1], 0, 0, 0);
                acc[vt][1] = __builtin_amdgcn_mfma_f32_16x16x32_bf16(A, B11, acc[vt][1], 0, 0, 0);
            } else {
                bf16x8 Ah = Z8, Al = Z8;
                if (row >= 0) {
                    const uint16_t* p = J.feat + (size_t)row * 64 + q * 8;
                    Ah = *(const bf16x8*)p;
                    Al = *(const bf16x8*)(p + 32);
                }
                acc[vt][0] = __builtin_amdgcn_mfma_f32_16x16x32_bf16(Ah, B00, acc[vt][0], 0, 0, 0);
                acc[vt][0] = __builtin_amdgcn_mfma_f32_16x16x32_bf16(Ah, B10, acc[vt][0], 0, 0, 0);
                acc[vt][0] = __builtin_amdgcn_mfma_f32_16x16x32_bf16(Al, B00, acc[vt][0], 0, 0, 0);
                acc[vt][1] = __builtin_amdgcn_mfma_f32_16x16x32_bf16(Ah, B01, acc[vt][1], 0, 0, 0);
                acc[vt][1] = __builtin_amdgcn_mfma_f32_16x16x32_bf16(Ah, B11, acc[vt][1], 0, 0, 0);
                acc[vt][1] = __builtin_amdgcn_mfma_f32_16x16x32_bf16(Al, B01, acc[vt][1], 0, 0, 0);
            }
        }
    }

    // epilogue: C layout col=lane&15 (out-ch), row=quad*4+reg (voxel)
#pragma unroll
    for (int ot = 0; ot < 2; ++ot) {
        int ch = ot * 16 + m;
        float ga = J.bn[ch], be = J.bn[32 + ch];
        float mu = J.bn[64 + ch], va = J.bn[96 + ch];
        float s = ga * rsqrtf(va + BN_EPS);
        float b = be - mu * s;
#pragma unroll
        for (int vt = 0; vt < 2; ++vt)
#pragma unroll
            for (int r = 0; r < 4; ++r) {
                int vox = n0 + vt0 + vt * 16 + q * 4 + r;
                if (vox >= N) continue;
                float x = acc[vt][ot][r];
                x = (x >= 0.f) ? x : SLOPE * x;
                float o = x * s + b;
                if (J.addsrc) {
                    o += bf2f(J.addsrc[(size_t)vox * 64 + ch]) +
                         bf2f(J.addsrc[(size_t)vox * 64 + 32 + ch]);
                }
                uint16_t h = f2bf(o);
                uint16_t l = f2bf(o - bf2f(h));
                J.out[(size_t)vox * 64 + ch]      = h;
                J.out[(size_t)vox * 64 + 32 + ch] = l;
            }
    }
}

// ---------------------------------------------------------------------------
// MFMA recon v2: 3 groups x 3 taps on y, BN scale pre-folded into Wf stage 4,
// sigmoid folded per group, gate-multiply by y (center = self).
// ---------------------------------------------------------------------------
__launch_bounds__(256, 3)
__global__ void recon_mfma2(const uint16_t* __restrict__ y,   // [N][64]
                            const int* __restrict__ nbr,
                            const uint16_t* __restrict__ Wf,  // stage-4 base
                            const float* __restrict__ Wc,
                            void* __restrict__ out_,
                            const int* __restrict__ flagp, int N)
{
    __shared__ int sidx[9][128];
    const int tid = threadIdx.x;
    const int n0  = blockIdx.x * 128;
    const int out_f32 = *flagp;

    const int rt[9] = {4, 13, 22, 10, 13, 16, 12, 13, 14};
    for (int i = tid; i < 9 * 128; i += 256) {
        int t = i >> 7, v = i & 127, n = n0 + v;
        sidx[t][v] = (n < N) ? nbr[(size_t)rt[t] * N + n] : -1;
    }
    __syncthreads();

    const int lane = tid & 63;
    const int m = lane & 15, q = lane >> 4;
    const int vt0 = (tid >> 6) * 32;
    const bf16x8 Z8 = {0, 0, 0, 0, 0, 0, 0, 0};

    f32x4 gsum[2][2];
#pragma unroll
    for (int vt = 0; vt < 2; ++vt)
#pragma unroll
        for (int ot = 0; ot < 2; ++ot) gsum[vt][ot] = {0.f, 0.f, 0.f, 0.f};

#pragma unroll
    for (int g = 0; g < 3; ++g) {
        f32x4 acc[2][2];
#pragma unroll
        for (int vt = 0; vt < 2; ++vt)
#pragma unroll
            for (int ot = 0; ot < 2; ++ot) acc[vt][ot] = {0.f, 0.f, 0.f, 0.f};

#pragma unroll
        for (int kk = 0; kk < 3; ++kk) {
            int t = g * 3 + kk;
            const uint16_t* wb = Wf + t * 2048;
            bf16x8 B00 = *(const bf16x8*)(wb +        m * 32 + q * 8);
            bf16x8 B10 = *(const bf16x8*)(wb + 1024 + m * 32 + q * 8);
            bf16x8 B01 = *(const bf16x8*)(wb +        (16 + m) * 32 + q * 8);
            bf16x8 B11 = *(const bf16x8*)(wb + 1024 + (16 + m) * 32 + q * 8);
#pragma unroll
            for (int vt = 0; vt < 2; ++vt) {
                int row = sidx[t][vt0 + vt * 16 + m];
                bf16x8 Ah = Z8, Al = Z8;
                if (row >= 0) {
                    const uint16_t* p = y + (size_t)row * 64 + q * 8;
                    Ah = *(const bf16x8*)p;
                    Al = *(const bf16x8*)(p + 32);
                }
                acc[vt][0] = __builtin_amdgcn_mfma_f32_16x16x32_bf16(Ah, B00, acc[vt][0], 0, 0, 0);
                acc[vt][0] = __builtin_amdgcn_mfma_f32_16x16x32_bf16(Ah, B10, acc[vt][0], 0, 0, 0);
                acc[vt][0] = __builtin_amdgcn_mfma_f32_16x16x32_bf16(Al, B00, acc[vt][0], 0, 0, 0);
                acc[vt][1] = __builtin_amdgcn_mfma_f32_16x16x32_bf16(Ah, B01, acc[vt][1], 0, 0, 0);
                acc[vt][1] = __builtin_amdgcn_mfma_f32_16x16x32_bf16(Ah, B11, acc[vt][1], 0, 0, 0);
                acc[vt][1] = __builtin_amdgcn_mfma_f32_16x16x32_bf16(Al, B01, acc[vt][1], 0, 0, 0);
            }
        }
        // fold sigmoid(acc + shift) into gsum; scale already folded in Wf
        const float* p = Wc + WC_BNP + (size_t)(4 + g) * 128;
#pragma unroll
        for (int ot = 0; ot < 2; ++ot) {
            int ch = ot * 16 + m;
            float scl = p[ch] * rsqrtf(p[96 + ch] + BN_EPS);
            float sh  = p[32 + ch] - p[64 + ch] * scl;
#pragma unroll
            for (int vt = 0; vt < 2; ++vt)
#pragma unroll
                for (int r = 0; r < 4; ++r) {
                    float x = acc[vt][ot][r] + sh;
                    gsum[vt][ot][r] += 1.f / (1.f + __expf(-x));
                }
        }
    }

#pragma unroll
    for (int ot = 0; ot < 2; ++ot) {
        int ch = ot * 16 + m;
#pragma unroll
        for (int vt = 0; vt < 2; ++vt)
#pragma unroll
            for (int r = 0; r < 4; ++r) {
                int vox = n0 + vt0 + vt * 16 + q * 4 + r;
                if (vox >= N) continue;
                float yv = bf2f(y[(size_t)vox * 64 + ch]) +
                           bf2f(y[(size_t)vox * 64 + 32 + ch]);
                float o = gsum[vt][ot][r] * yv;
                if (out_f32)
                    ((float*)out_)[(size_t)vox * 32 + ch] = o;
                else
                    ((uint16_t*)out_)[(size_t)vox * 32 + ch] = f2bf(o);
            }
    }
}

// ---------------------------------------------------------------------------
// Fallback VALU kernels (round-4 proven) for tiny-ws tier.
// ---------------------------------------------------------------------------
template<int CIN>
__launch_bounds__(256)
__global__ void conv_bn_lrelu_bf(const uint16_t* __restrict__ feat,
                                 const int* __restrict__ nbr,
                                 const float* __restrict__ Wg,
                                 const float* __restrict__ bnp,
                                 const uint16_t* __restrict__ addsrc,
                                 uint16_t* __restrict__ out,
                                 Taps9 taps, int N)
{
    __shared__ float Wl[9 * CIN * 32];
    __shared__ float fs[CIN][128];
    __shared__ int   sidx[128];
    __shared__ float bns[32], bnb[32];

    const int tid = threadIdx.x;
    const int n0  = blockIdx.x * 128;

    for (int i = tid; i < 9 * CIN * 32; i += 256) Wl[i] = Wg[i];
    if (tid < 32) {
        float g = bnp[tid], b = bnp[32 + tid];
        float mu = bnp[64 + tid], va = bnp[96 + tid];
        float s = g * rsqrtf(va + BN_EPS);
        bns[tid] = s; bnb[tid] = b - mu * s;
    }
    float acc[4][4];
#pragma unroll
    for (int v = 0; v < 4; ++v)
#pragma unroll
        for (int j = 0; j < 4; ++j) acc[v][j] = 0.f;

    const int vb = (tid >> 3) << 2, cg = (tid & 7) << 2;
    const int r = tid >> 1, h = tid & 1, j0 = h * (CIN / 2);

#pragma unroll 1
    for (int t = 0; t < 9; ++t) {
        __syncthreads();
        if (tid < 128) {
            int n = n0 + tid;
            sidx[tid] = (n < N) ? nbr[(size_t)taps.t[t] * N + n] : -1;
        }
        __syncthreads();
        int mm = sidx[r];
        if (mm >= 0) {
            const uint16_t* src = feat + (size_t)mm * CIN + j0;
#pragma unroll
            for (int qq = 0; qq < CIN / 2; qq += 8) {
                uint4 u = *reinterpret_cast<const uint4*>(src + qq);
                fs[j0 + qq + 0][r] = bflo(u.x); fs[j0 + qq + 1][r] = bfhi(u.x);
                fs[j0 + qq + 2][r] = bflo(u.y); fs[j0 + qq + 3][r] = bfhi(u.y);
                fs[j0 + qq + 4][r] = bflo(u.z); fs[j0 + qq + 5][r] = bfhi(u.z);
                fs[j0 + qq + 6][r] = bflo(u.w); fs[j0 + qq + 7][r] = bfhi(u.w);
            }
        } else {
#pragma unroll
            for (int qq = 0; qq < CIN / 2; ++qq) fs[j0 + qq][r] = 0.f;
        }
        __syncthreads();
        const float* wk = Wl + t * (CIN * 32) + cg;
#pragma unroll
        for (int ci = 0; ci < CIN; ++ci) {
            float4 f = *reinterpret_cast<const float4*>(&fs[ci][vb]);
            float4 w = *reinterpret_cast<const float4*>(wk + ci * 32);
            acc[0][0] += f.x * w.x; acc[0][1] += f.x * w.y; acc[0][2] += f.x * w.z; acc[0][3] += f.x * w.w;
            acc[1][0] += f.y * w.x; acc[1][1] += f.y * w.y; acc[1][2] += f.y * w.z; acc[1][3] += f.y * w.w;
            acc[2][0] += f.z * w.x; acc[2][1] += f.z * w.y; acc[2][2] += f.z * w.z; acc[2][3] += f.z * w.w;
            acc[3][0] += f.w * w.x; acc[3][1] += f.w * w.y; acc[3][2] += f.w * w.z; acc[3][3] += f.w * w.w;
        }
    }
#pragma unroll
    for (int v = 0; v < 4; ++v) {
        int n = n0 + vb + v;
        if (n >= N) continue;
        ushort4 st;
        uint16_t* ov = (uint16_t*)&st;
#pragma unroll
        for (int j = 0; j < 4; ++j) {
            float x = acc[v][j];
            x = (x >= 0.f) ? x : SLOPE * x;
            float o = x * bns[cg + j] + bnb[cg + j];
            if (addsrc) o += bf2f(addsrc[(size_t)n * 32 + cg + j]);
            ov[j] = f2bf(o);
        }
        *reinterpret_cast<ushort4*>(out + (size_t)n * 32 + cg) = st;
    }
}

__launch_bounds__(256, 4)
__global__ void recon_gate_bf(const uint16_t* __restrict__ y,
                              const int* __restrict__ nbr,
                              const float* __restrict__ Wc,
                              void* __restrict__ out_,
                              const int* __restrict__ flagp, int N)
{
    __shared__ float Wl[3 * 32 * 32];
    __shared__ float fs[32][128];
    __shared__ int   sidx[128];
    __shared__ float scl[3][32], shf[3][32];

    const int tid = threadIdx.x;
    const int n0  = blockIdx.x * 128;
    const int out_f32 = *flagp;

    if (tid < 96) {
        int g = tid >> 5, c = tid & 31;
        const float* p = Wc + WC_BNP + (size_t)(4 + g) * 128;
        float ga = p[c], be = p[32 + c], mu = p[64 + c], va = p[96 + c];
        float s = ga * rsqrtf(va + BN_EPS);
        scl[g][c] = s; shf[g][c] = be - mu * s;
    }
    const int vb = (tid >> 3) << 2, cg = (tid & 7) << 2;
    const int r = tid >> 1, h = tid & 1, j0 = h * 16;

    float gsum[4][4];
#pragma unroll
    for (int v = 0; v < 4; ++v)
#pragma unroll
        for (int j = 0; j < 4; ++j) gsum[v][j] = 0.f;

    const int taps[3][3] = {{4, 13, 22}, {10, 13, 16}, {12, 13, 14}};

#pragma unroll 1
    for (int g = 0; g < 3; ++g) {
        __syncthreads();
        {
            const float* src = Wc + WC_WR1 + g * 3072;
            for (int i = tid; i < 3072; i += 256)
                Wl[i] = src[i] * scl[g][i & 31];
        }
        float acc[4][4];
#pragma unroll
        for (int v = 0; v < 4; ++v)
#pragma unroll
            for (int j = 0; j < 4; ++j) acc[v][j] = 0.f;

#pragma unroll 1
        for (int k = 0; k < 3; ++k) {
            __syncthreads();
            if (tid < 128) {
                int n = n0 + tid;
                sidx[tid] = (n < N) ? nbr[(size_t)taps[g][k] * N + n] : -1;
            }
            __syncthreads();
            int mm = sidx[r];
            if (mm >= 0) {
                const uint16_t* src = y + (size_t)mm * 32 + j0;
#pragma unroll
                for (int qq = 0; qq < 16; qq += 8) {
                    uint4 u = *reinterpret_cast<const uint4*>(src + qq);
                    fs[j0 + qq + 0][r] = bflo(u.x); fs[j0 + qq + 1][r] = bfhi(u.x);
                    fs[j0 + qq + 2][r] = bflo(u.y); fs[j0 + qq + 3][r] = bfhi(u.y);
                    fs[j0 + qq + 4][r] = bflo(u.z); fs[j0 + qq + 5][r] = bfhi(u.z);
                    fs[j0 + qq + 6][r] = bflo(u.w); fs[j0 + qq + 7][r] = bfhi(u.w);
                }
            } else {
#pragma unroll
                for (int qq = 0; qq < 16; ++qq) fs[j0 + qq][r] = 0.f;
            }
            __syncthreads();
            const float* wk = Wl + k * (32 * 32) + cg;
#pragma unroll
            for (int ci = 0; ci < 32; ++ci) {
                float4 f = *reinterpret_cast<const float4*>(&fs[ci][vb]);
                float4 w = *reinterpret_cast<const float4*>(wk + ci * 32);
                acc[0][0] += f.x * w.x; acc[0][1] += f.x * w.y; acc[0][2] += f.x * w.z; acc[0][3] += f.x * w.w;
                acc[1][0] += f.y * w.x; acc[1][1] += f.y * w.y; acc[1][2] += f.y * w.z; acc[1][3] += f.y * w.w;
                acc[2][0] += f.z * w.x; acc[2][1] += f.z * w.y; acc[2][2] += f.z * w.z; acc[2][3] += f.z * w.w;
                acc[3][0] += f.w * w.x; acc[3][1] += f.w * w.y; acc[3][2] += f.w * w.z; acc[3][3] += f.w * w.w;
            }
        }
#pragma unroll
        for (int v = 0; v < 4; ++v)
#pragma unroll
            for (int j = 0; j < 4; ++j) {
                float x = acc[v][j] + shf[g][cg + j];
                gsum[v][j] += 1.f / (1.f + __expf(-x));
            }
    }
#pragma unroll
    for (int v = 0; v < 4; ++v) {
        int n = n0 + vb + v;
        if (n >= N) continue;
#pragma unroll
        for (int j = 0; j < 4; ++j) {
            float yv = bf2f(y[(size_t)n * 32 + cg + j]);
            float o = gsum[v][j] * yv;
            if (out_f32) ((float*)out_)[(size_t)n * 32 + cg + j] = o;
            else ((uint16_t*)out_)[(size_t)n * 32 + cg + j] = f2bf(o);
        }
    }
}

// ---------------------------------------------------------------------------
extern "C" void kernel_launch(void* const* d_in, const int* in_sizes, int n_in,
                              void* d_out, int out_size, void* d_ws, size_t ws_size,
                              hipStream_t stream)
{
    (void)n_in; (void)out_size;
    const void* x   = d_in[0];
    const int*  nbr = (const int*)d_in[1];
    const int N  = in_sizes[0] / 16;

    int*      flag = (int*)d_ws;
    float*    Wc   = (float*)d_ws + 64;
    const size_t hdrB  = 37888u * 4u;
    uint16_t* Wf   = (uint16_t*)((char*)d_ws + hdrB);
    const size_t prepB = (size_t)WF_TOTAL * 2;     // 184320
    const size_t base2 = hdrB + prepB;
    const size_t xhlB  = (size_t)N * 64;           // 9.6 MB
    const size_t plnB  = (size_t)N * 128;          // 19.2 MB

    dim3 block(256);
    const int gx = (N + 127) / 128;
    Taps9 p133 = {{9, 10, 11, 12, 13, 14, 15, 16, 17}};
    Taps9 p313 = {{3, 4, 5, 12, 13, 14, 21, 22, 23}};
    WSrcs ws8 = {{ d_in[2], d_in[3], d_in[4], d_in[5],
                   d_in[6], d_in[7], d_in[8], d_in[9] }};

    detect_dtype<<<1, 256, 0, stream>>>((const uint16_t*)x, flag);
    canon_weights<<<(WC_END + 255) / 256, 256, 0, stream>>>(ws8, Wc, flag);

    const float* bn0 = Wc + WC_BNP + 0 * 128;
    const float* bn1 = Wc + WC_BNP + 1 * 128;
    const float* bn2 = Wc + WC_BNP + 2 * 128;
    const float* bn3 = Wc + WC_BNP + 3 * 128;

    if (ws_size >= base2 + xhlB + 4 * plnB) {
        // Fused MFMA tier
        prep_weights<<<(WF_TOTAL + 255) / 256, 256, 0, stream>>>(Wc, Wf);
        uint16_t* xhl = (uint16_t*)((char*)d_ws + base2);
        uint16_t* A1  = xhl + (size_t)N * 32;
        uint16_t* A2  = A1 + (size_t)N * 64;
        uint16_t* B1  = A2 + (size_t)N * 64;
        uint16_t* B2  = B1 + (size_t)N * 64;
        canon_x_hl<<<1024, 256, 0, stream>>>(x, xhl, N, flag);
        ConvJob c1  = {xhl, Wf + 0 * WF_STAGE, bn0, nullptr, A1, p133};
        ConvJob c2  = {xhl, Wf + 2 * WF_STAGE, bn2, nullptr, A2, p313};
        ConvJob c12 = {A1,  Wf + 1 * WF_STAGE, bn1, nullptr, B1, p313};
        ConvJob c3  = {A2,  Wf + 3 * WF_STAGE, bn3, nullptr, B2, p133};
        conv_mfma2<16><<<dim3(gx, 2), block, 0, stream>>>(c1, c2, nbr, N);
        conv_mfma2<32><<<dim3(gx, 2), block, 0, stream>>>(c12, c3, nbr, N);
        add_y<<<1024, 256, 0, stream>>>(B1, B2, B1, N * 4);
        recon_mfma2<<<gx, block, 0, stream>>>(B1, nbr, Wf + 4 * WF_STAGE, Wc, d_out, flag, N);
    } else if (ws_size >= base2 + xhlB + 2 * plnB) {
        // Sequential MFMA tier (round-5 structure, v2 kernels)
        prep_weights<<<(WF_TOTAL + 255) / 256, 256, 0, stream>>>(Wc, Wf);
        uint16_t* xhl = (uint16_t*)((char*)d_ws + base2);
        uint16_t* A   = xhl + (size_t)N * 32;
        uint16_t* B   = A + (size_t)N * 64;
        canon_x_hl<<<1024, 256, 0, stream>>>(x, xhl, N, flag);
        ConvJob c1  = {xhl, Wf + 0 * WF_STAGE, bn0, nullptr, A, p133};
        ConvJob c12 = {A,   Wf + 1 * WF_STAGE, bn1, nullptr, B, p313};
        ConvJob c2  = {xhl, Wf + 2 * WF_STAGE, bn2, nullptr, A, p313};
        ConvJob c3  = {A,   Wf + 3 * WF_STAGE, bn3, B,       B, p133};
        conv_mfma2<16><<<dim3(gx, 1), block, 0, stream>>>(c1, c1, nbr, N);
        conv_mfma2<32><<<dim3(gx, 1), block, 0, stream>>>(c12, c12, nbr, N);
        conv_mfma2<16><<<dim3(gx, 1), block, 0, stream>>>(c2, c2, nbr, N);
        conv_mfma2<32><<<dim3(gx, 1), block, 0, stream>>>(c3, c3, nbr, N);
        recon_mfma2<<<gx, block, 0, stream>>>(B, nbr, Wf + 4 * WF_STAGE, Wc, d_out, flag, N);
    } else {
        // VALU fallback tier (all-bf16)
        uint16_t* xc = (uint16_t*)((char*)d_ws + hdrB);
        uint16_t* A  = (uint16_t*)d_out;
        uint16_t* B  = xc + (size_t)N * 16;
        canon_x_bf<<<1024, 256, 0, stream>>>(x, xc, N * 16, flag);
        conv_bn_lrelu_bf<16><<<gx, block, 0, stream>>>(xc, nbr, Wc + WC_W1,  bn0, nullptr, A, p133, N);
        conv_bn_lrelu_bf<32><<<gx, block, 0, stream>>>(A,  nbr, Wc + WC_W12, bn1, nullptr, B, p313, N);
        conv_bn_lrelu_bf<16><<<gx, block, 0, stream>>>(xc, nbr, Wc + WC_W2,  bn2, nullptr, A, p313, N);
        conv_bn_lrelu_bf<32><<<gx, block, 0, stream>>>(A,  nbr, Wc + WC_W3,  bn3, B,       B, p133, N);
        recon_gate_bf<<<gx, block, 0, stream>>>(B, nbr, Wc, d_out, flag, N);
    }
}